// Round 8
// baseline (711.188 us; speedup 1.0000x reference)
//
#include <hip/hip_runtime.h>
#include <hip/hip_bf16.h>

#define DIM 64
#define SCAN_CHUNK 2048
#define NCH 128        // edge chunks per side (LDS-histogram build)
#define HWORDS 32768   // 128 KB static LDS histogram

typedef __bf16 bf16v8 __attribute__((ext_vector_type(8)));
typedef float f32v4 __attribute__((ext_vector_type(4)));

static inline int idiv(int a, int b) { return (a + b - 1) / b; }

__device__ inline unsigned short f2b(float f) {
    __hip_bfloat16 h = __float2bfloat16(f);
    return *reinterpret_cast<unsigned short*>(&h);
}
__device__ inline float b2f(unsigned short u) {
    __hip_bfloat16 h;
    *reinterpret_cast<unsigned short*>(&h) = u;
    return __bfloat162float(h);
}

// ================= LDS byte-histogram CSR build (mega path) =================
// cnt layout: [2][NCH][N] bytes (row side then col side), aliased onto bufC+bufD.

// Phase 1: per-(chunk,node) counts; whole node range in byte-packed LDS.
__global__ __launch_bounds__(1024, 1) void k_hist1(const int* __restrict__ row,
                                                   const int* __restrict__ col,
                                                   unsigned char* __restrict__ cnt,
                                                   int E, int N, int C) {
    __shared__ int hsh[HWORDS];
    int b = blockIdx.x;              // 0..2*NCH-1
    int side = b >> 7;
    int lb = b & (NCH - 1);
    const int* key = side ? col : row;
    int words = (N + 3) >> 2;
    for (int i = threadIdx.x; i < words; i += blockDim.x) hsh[i] = 0;
    __syncthreads();
    int e0 = lb * C, e1 = min(e0 + C, E);
    for (int e = e0 + threadIdx.x; e < e1; e += blockDim.x) {
        int v = key[e];
        atomicAdd(&hsh[v >> 2], 1 << ((v & 3) * 8));
    }
    __syncthreads();
    int* my = (int*)(cnt + (size_t)b * N);   // N%4==0 guaranteed by host gate
    int nw = N >> 2;
    for (int i = threadIdx.x; i < nw; i += blockDim.x) my[i] = hsh[i];
}

// Phase 2: per-node exclusive prefix over the NCH chunks (byte offsets, in
// place) + total degree.
__global__ __launch_bounds__(256) void k_prefixB(unsigned char* __restrict__ cnt,
                                                 int* __restrict__ degs, int N) {
    int v = blockIdx.x * blockDim.x + threadIdx.x;
    if (v < 2 * N) {
        int side = (v >= N) ? 1 : 0;
        int node = v - side * N;
        unsigned char* p = cnt + (size_t)side * NCH * N + node;
        int s = 0;
#pragma unroll 8
        for (int b = 0; b < NCH; b++) {
            unsigned char c = p[(size_t)b * N];
            p[(size_t)b * N] = (unsigned char)s;
            s += c;
        }
        degs[v] = s;
    }
}

// Phase 3: replay histogram; old BYTE = unique within-(chunk,node) slot.
// Scatter uses NON-TEMPORAL stores: no L2 allocate -> no read-for-ownership
// line fills (r7 counters: 194MB FETCH vs ~55MB analytic = RFO overhead).
__global__ __launch_bounds__(1024, 1) void k_fill3(const int* __restrict__ row,
        const int* __restrict__ col,
        const int* __restrict__ rptr, const int* __restrict__ cptr,
        const unsigned char* __restrict__ cnt,
        const int* __restrict__ deg_r, const int* __restrict__ deg_c,
        unsigned* __restrict__ adj, unsigned* __restrict__ adjT,
        int E, int N, int C, int idxbits) {
    __shared__ int hsh[HWORDS];
    int b = blockIdx.x;
    int side = b >> 7;
    int lb = b & (NCH - 1);
    const int* key = side ? col : row;
    const int* oth = side ? row : col;
    const int* ptr = side ? cptr : rptr;
    const int* odeg = side ? deg_r : deg_c;
    unsigned* dst = side ? adjT : adj;
    const unsigned char* my = cnt + (size_t)b * N;
    int words = (N + 3) >> 2;
    for (int i = threadIdx.x; i < words; i += blockDim.x) hsh[i] = 0;
    __syncthreads();
    unsigned dmask = (1u << (32 - idxbits)) - 1u;
    int e0 = lb * C, e1 = min(e0 + C, E);
    for (int e = e0 + threadIdx.x; e < e1; e += blockDim.x) {
        int v = key[e];
        int sh = (v & 3) * 8;
        unsigned old = (unsigned)atomicAdd(&hsh[v >> 2], 1 << sh);
        int slot = (int)((old >> sh) & 255u);
        int o = oth[e];
        unsigned d = min((unsigned)odeg[o], dmask);
        __builtin_nontemporal_store((unsigned)o | (d << idxbits),
                                    &dst[ptr[v] + (int)my[v] + slot]);
    }
}

// ================= legacy atomic build (fallback path) =================
__global__ void k_degrees(const int* __restrict__ row, const int* __restrict__ col,
                          int* __restrict__ dr, int* __restrict__ dc,
                          unsigned* __restrict__ slot, int E) {
    int e = blockIdx.x * blockDim.x + threadIdx.x;
    if (e < E) {
        unsigned sr = (unsigned)atomicAdd(&dr[row[e]], 1);
        unsigned sc = (unsigned)atomicAdd(&dc[col[e]], 1);
        slot[e] = (sr & 0xFFFFu) | (sc << 16);
    }
}

__global__ void k_fill(const int* __restrict__ row, const int* __restrict__ col,
                       const int* __restrict__ rptr, const int* __restrict__ cptr,
                       const unsigned* __restrict__ slot,
                       const int* __restrict__ deg_r, const int* __restrict__ deg_c,
                       unsigned* __restrict__ adj, unsigned* __restrict__ adjT,
                       int E, int idxbits) {
    int e = blockIdx.x * blockDim.x + threadIdx.x;
    if (e < E) {
        int r = row[e], c = col[e];
        unsigned s = slot[e];
        unsigned sr = s & 0xFFFFu;
        unsigned sc = s >> 16;
        unsigned wmask = (1u << (32 - idxbits)) - 1u;
        unsigned wc = (unsigned)min((unsigned)deg_c[c], wmask);
        unsigned wr = (unsigned)min((unsigned)deg_r[r], wmask);
        adj [rptr[r] + sr] = (unsigned)c | (wc << idxbits);
        adjT[cptr[c] + sc] = (unsigned)r | (wr << idxbits);
    }
}

// ================= scans =================
__global__ __launch_bounds__(256) void k_scan_blk(const int* __restrict__ deg_r,
                                                  const int* __restrict__ deg_c,
                                                  int* __restrict__ part, int n, int G) {
    int b = blockIdx.x;
    const int* deg = (b < G) ? deg_r : deg_c;
    int lb = (b < G) ? b : b - G;
    int base = lb * SCAN_CHUNK;
    int t = threadIdx.x;
    int s = 0;
    for (int i = t; i < SCAN_CHUNK; i += 256) {
        int g = base + i;
        if (g < n) s += deg[g];
    }
    __shared__ int red[256];
    red[t] = s;
    __syncthreads();
    for (int off = 128; off > 0; off >>= 1) {
        if (t < off) red[t] += red[t + off];
        __syncthreads();
    }
    if (t == 0) part[b] = red[0];
}

__global__ __launch_bounds__(1024) void k_scan_top(int* __restrict__ part, int G,
        const float* __restrict__ bs_sd, const float* __restrict__ b0_sd,
        const float* __restrict__ bs_ds, const float* __restrict__ b0_ds,
        float* __restrict__ cb) {
    int t = threadIdx.x;
    if (blockIdx.x == 2) {
        if (t < 64) {
            float ssd = bs_sd[t] + b0_sd[t];
            float sds = bs_ds[t] + b0_ds[t];
            float sc = 1.f;
            for (int i = 1; i < 4; i++) {
                sc *= 0.5f;
                ssd += bs_sd[i * 64 + t] * sc;
                sds += bs_ds[i * 64 + t] * sc;
            }
            cb[t] = 0.5f * ssd + 0.5f * sds;  // ALPHA = 0.5
        }
        return;
    }
    int* p = part + ((blockIdx.x == 0) ? 0 : G);
    __shared__ int sums[1024];
    sums[t] = (t < G) ? p[t] : 0;
    __syncthreads();
    for (int off = 1; off < 1024; off <<= 1) {
        int v = (t >= off) ? sums[t - off] : 0;
        __syncthreads();
        sums[t] += v;
        __syncthreads();
    }
    if (t < G) p[t] = (t == 0) ? 0 : sums[t - 1];
}

__global__ __launch_bounds__(256) void k_scan_fin(const int* __restrict__ deg_r,
                                                  const int* __restrict__ deg_c,
                                                  const int* __restrict__ part,
                                                  int* __restrict__ rptr, int* __restrict__ cptr,
                                                  float* __restrict__ inv_r, float* __restrict__ inv_c,
                                                  int n, int G) {
    int b = blockIdx.x;
    bool isr = (b < G);
    const int* deg = isr ? deg_r : deg_c;
    int* ptr = isr ? rptr : cptr;
    float* inv = isr ? inv_r : inv_c;
    int lb = isr ? b : b - G;
    int off = part[b];
    int base = lb * SCAN_CHUNK;
    int t = threadIdx.x;
    int start = base + t * 8;
    int v[8];
    int s = 0;
#pragma unroll
    for (int k = 0; k < 8; k++) {
        int g = start + k;
        int d = (g < n) ? deg[g] : 0;
        v[k] = d;
        s += d;
    }
    __shared__ int sums[256];
    sums[t] = s;
    __syncthreads();
    for (int o = 1; o < 256; o <<= 1) {
        int x = (t >= o) ? sums[t - o] : 0;
        __syncthreads();
        sums[t] += x;
        __syncthreads();
    }
    int run = off + ((t == 0) ? 0 : sums[t - 1]);
#pragma unroll
    for (int k = 0; k < 8; k++) {
        int g = start + k;
        if (g < n) {
            ptr[g] = run;
            inv[g] = (v[k] > 0) ? rsqrtf((float)v[k]) : 0.f;
            run += v[k];
        }
    }
    if (t == 255 && lb == G - 1) ptr[n] = run;  // grand total
}

// ================= misc prep =================
__global__ void k_xcast(const float* __restrict__ x, unsigned short* __restrict__ xb, int total) {
    int i = (blockIdx.x * blockDim.x + threadIdx.x) * 4;
    if (i < total) {
        float4 v = *reinterpret_cast<const float4*>(x + i);
        ushort4 o;
        o.x = f2b(v.x); o.y = f2b(v.y); o.z = f2b(v.z); o.w = f2b(v.w);
        *reinterpret_cast<ushort4*>(xb + i) = o;
    }
}

__global__ void k_wprep(const float* __restrict__ Ws_sd, const float* __restrict__ Ws_ds,
                        const float* __restrict__ W0_sd, const float* __restrict__ W0_ds,
                        unsigned short* __restrict__ Wall) {
    int i = blockIdx.x * blockDim.x + threadIdx.x;  // 9*4096 total
    if (i >= 9 * 4096) return;
    int m = i >> 12, src = i & 4095;
    float v;
    if (m == 0) {
        v = 0.5f * (W0_sd[src] + W0_ds[src]);
    } else if (m < 5) {
        int hop = m - 1;
        v = Ws_sd[hop * 4096 + src] * (0.5f / (float)(1 << hop));
    } else {
        int hop = m - 5;
        v = Ws_ds[hop * 4096 + src] * (0.5f / (float)(1 << hop));
    }
    Wall[i] = f2b(v);
}

// ================= SpMM (proven body; nt adj stream + nt out store to keep
// the hot h gather table resident in L2) =================
__global__ __launch_bounds__(256) void k_spmm(const unsigned short* __restrict__ h,
                                              unsigned short* __restrict__ out,
                                              const int* __restrict__ ptr,
                                              const unsigned* __restrict__ adj,
                                              const float* __restrict__ inv_self,
                                              int n, int idxbits) {
    int gw = (blockIdx.x * blockDim.x + threadIdx.x) >> 6;
    int lane = threadIdx.x & 63;
    if (gw >= n) return;
    int beg = ptr[gw], end = ptr[gw + 1];
    unsigned imask = (1u << idxbits) - 1u;
    float acc = 0.f;
#pragma unroll 8
    for (int j = beg; j < end; j++) {
        unsigned p = __builtin_nontemporal_load(adj + j);
        float w = rsqrtf((float)(p >> idxbits));
        acc = fmaf(w, b2f(h[(size_t)(p & imask) * DIM + lane]), acc);
    }
    __builtin_nontemporal_store(f2b(inv_self[gw] * acc), &out[gw * DIM + lane]);
}

__global__ __launch_bounds__(256) void k_spmm_acc(const unsigned short* __restrict__ h,
                                                  float* __restrict__ out,
                                                  const int* __restrict__ ptr,
                                                  const unsigned* __restrict__ adj,
                                                  const float* __restrict__ inv_self,
                                                  int n, int idxbits) {
    int gw = (blockIdx.x * blockDim.x + threadIdx.x) >> 6;
    int lane = threadIdx.x & 63;
    if (gw >= n) return;
    int beg = ptr[gw], end = ptr[gw + 1];
    unsigned imask = (1u << idxbits) - 1u;
    float acc = 0.f;
#pragma unroll 8
    for (int j = beg; j < end; j++) {
        unsigned p = __builtin_nontemporal_load(adj + j);
        float w = rsqrtf((float)(p >> idxbits));
        acc = fmaf(w, b2f(h[(size_t)(p & imask) * DIM + lane]), acc);
    }
    out[gw * DIM + lane] += inv_self[gw] * acc;
}

// ================= multi-matrix MFMA GEMM =================
template <int NM, bool INIT, bool BF16OUT>
__global__ __launch_bounds__(256, 2) void k_mg(
        const unsigned short* __restrict__ h0, const unsigned short* __restrict__ h1,
        const unsigned short* __restrict__ h2, const unsigned short* __restrict__ h3,
        const unsigned short* __restrict__ h4,
        const unsigned short* __restrict__ W0, const unsigned short* __restrict__ W1,
        const unsigned short* __restrict__ W2, const unsigned short* __restrict__ W3,
        const unsigned short* __restrict__ W4,
        const float* __restrict__ cb, void* __restrict__ outv, int n) {
    const unsigned short* hs[5] = {h0, h1, h2, h3, h4};
    const unsigned short* Ws[5] = {W0, W1, W2, W3, W4};
    float* outf = (float*)outv;
    unsigned short* outb = (unsigned short*)outv;
    int lane = threadIdx.x & 63;
    int quad = lane >> 4;
    int l16 = lane & 15;
    int nmax = n - 1;

    bf16v8 w[NM][4][2];
#pragma unroll
    for (int m = 0; m < NM; m++)
#pragma unroll
        for (int ot = 0; ot < 4; ot++)
#pragma unroll
            for (int kh = 0; kh < 2; kh++)
                w[m][ot][kh] = *reinterpret_cast<const bf16v8*>(
                    Ws[m] + (size_t)(ot * 16 + l16) * 64 + kh * 32 + quad * 8);

    float bias[4];
    if (INIT) {
#pragma unroll
        for (int ot = 0; ot < 4; ot++) bias[ot] = cb ? cb[ot * 16 + l16] : 0.f;
    }
    int tiles_all = (n + 15) >> 4;
    int wave = (blockIdx.x * blockDim.x + threadIdx.x) >> 6;
    int nw = (gridDim.x * blockDim.x) >> 6;
    for (int t = wave; t < tiles_all; t += nw) {
        int row0 = t << 4;
        int arow = min(row0 + l16, nmax);
        bf16v8 a[NM][2];
#pragma unroll
        for (int m = 0; m < NM; m++) {
            const bf16v8* p = reinterpret_cast<const bf16v8*>(hs[m] + (size_t)arow * 64 + quad * 8);
            a[m][0] = p[0];
            a[m][1] = p[4];
        }
        f32v4 acc[4];
        if (INIT) {
#pragma unroll
            for (int ot = 0; ot < 4; ot++) {
                float b = bias[ot];
                acc[ot] = f32v4{b, b, b, b};
            }
        } else {
#pragma unroll
            for (int ot = 0; ot < 4; ot++)
#pragma unroll
                for (int r = 0; r < 4; r++)
                    acc[ot][r] = outf[(size_t)min(row0 + quad * 4 + r, nmax) * 64 + ot * 16 + l16];
        }
#pragma unroll
        for (int ot = 0; ot < 4; ot++)
#pragma unroll
            for (int m = 0; m < NM; m++) {
                acc[ot] = __builtin_amdgcn_mfma_f32_16x16x32_bf16(a[m][0], w[m][ot][0], acc[ot], 0, 0, 0);
                acc[ot] = __builtin_amdgcn_mfma_f32_16x16x32_bf16(a[m][1], w[m][ot][1], acc[ot], 0, 0, 0);
            }
#pragma unroll
        for (int ot = 0; ot < 4; ot++)
#pragma unroll
            for (int r = 0; r < 4; r++) {
                int rr = row0 + quad * 4 + r;
                if (rr < n) {
                    if (BF16OUT) outb[(size_t)rr * 64 + ot * 16 + l16] = f2b(acc[ot][r]);
                    else         outf[(size_t)rr * 64 + ot * 16 + l16] = acc[ot][r];
                }
            }
    }
}

extern "C" void kernel_launch(void* const* d_in, const int* in_sizes, int n_in,
                              void* d_out, int out_size, void* d_ws, size_t ws_size,
                              hipStream_t stream) {
    const float* x     = (const float*)d_in[0];
    const int*   ei    = (const int*)d_in[1];
    const float* Ws_sd = (const float*)d_in[2];
    const float* bs_sd = (const float*)d_in[3];
    const float* Ws_ds = (const float*)d_in[4];
    const float* bs_ds = (const float*)d_in[5];
    const float* W0_sd = (const float*)d_in[6];
    const float* b0_sd = (const float*)d_in[7];
    const float* W0_ds = (const float*)d_in[8];
    const float* b0_ds = (const float*)d_in[9];

    int N = in_sizes[0] / DIM;
    int E = in_sizes[1] / 2;
    const int* row = ei;
    const int* col = ei + E;
    float* out = (float*)d_out;

    int G = idiv(N, SCAN_CHUNK);
    int idxbits = 1;
    while ((1 << idxbits) < N) idxbits++;

    char* wsp = (char*)d_ws;
    auto alloc = [&](size_t bytes) -> void* {
        void* p = (void*)wsp;
        wsp += ((bytes + 63) / 64) * 64;
        return p;
    };
    size_t bufBytes = ((((size_t)N * DIM * 2) + 63) / 64) * 64;

    int* degs   = (int*)alloc((size_t)2 * N * 4);
    int* deg_r  = degs;
    int* deg_c  = degs + N;
    int* rptr   = (int*)alloc(((size_t)N + 1) * 4);
    int* cptr   = (int*)alloc(((size_t)N + 1) * 4);
    unsigned* adj  = (unsigned*)alloc((size_t)E * 4);
    unsigned* adjT = (unsigned*)alloc((size_t)E * 4);
    unsigned short* xb = (unsigned short*)alloc((size_t)N * DIM * 2);
    float* invs = (float*)alloc((size_t)2 * N * 4);
    float* inv_r = invs;
    float* inv_c = invs + N;
    float* cb   = (float*)alloc(64 * 4);
    unsigned short* Wall = (unsigned short*)alloc((size_t)9 * 4096 * 2);
    int* part   = (int*)alloc((size_t)2 * G * 4);
    unsigned* slot = (unsigned*)alloc((size_t)E * 4);   // fallback path only
    unsigned short* zb = (unsigned short*)alloc((size_t)N * DIM * 2);

    size_t fixed_used = (size_t)(wsp - (char*)d_ws);
    bool mega = (fixed_used + 4 * bufBytes) <= ws_size;

    unsigned short* bufA = (unsigned short*)alloc((size_t)N * DIM * 2);
    unsigned short* bufB = (unsigned short*)alloc((size_t)N * DIM * 2);
    unsigned short* bufC = mega ? (unsigned short*)alloc((size_t)N * DIM * 2) : nullptr;
    unsigned short* bufD = mega ? (unsigned short*)alloc((size_t)N * DIM * 2) : nullptr;

    // cnt [2][NCH][N] bytes = 256N aliases bufC+bufD (= 2*128N bytes, exact fit);
    // consumed by k_fill3 before y2/y3 first write bufC/bufD.
    unsigned char* cnt = (unsigned char*)bufC;
    bool ldsb = mega && (N <= HWORDS * 4) && ((N & 3) == 0);
    int C = idiv(E, NCH);

    if (ldsb) {
        k_hist1<<<2 * NCH, 1024, 0, stream>>>(row, col, cnt, E, N, C);
        k_prefixB<<<idiv(2 * N, 256), 256, 0, stream>>>(cnt, degs, N);
    } else {
        hipMemsetAsync(degs, 0, (size_t)2 * N * sizeof(int), stream);
        k_degrees<<<idiv(E, 256), 256, 0, stream>>>(row, col, deg_r, deg_c, slot, E);
    }
    k_scan_blk<<<2 * G, 256, 0, stream>>>(deg_r, deg_c, part, N, G);
    k_scan_top<<<3, 1024, 0, stream>>>(part, G, bs_sd, b0_sd, bs_ds, b0_ds, cb);
    k_scan_fin<<<2 * G, 256, 0, stream>>>(deg_r, deg_c, part, rptr, cptr, inv_r, inv_c, N, G);
    if (ldsb) {
        k_fill3<<<2 * NCH, 1024, 0, stream>>>(row, col, rptr, cptr, cnt,
                                              deg_r, deg_c, adj, adjT, E, N, C, idxbits);
    } else {
        k_fill<<<idiv(E, 256), 256, 0, stream>>>(row, col, rptr, cptr, slot,
                                                 deg_r, deg_c, adj, adjT, E, idxbits);
    }
    k_xcast<<<idiv(N * DIM / 4, 256), 256, 0, stream>>>(x, xb, N * DIM);
    k_wprep<<<144, 256, 0, stream>>>(Ws_sd, Ws_ds, W0_sd, W0_ds, Wall);

    const unsigned short* W0c = Wall;
    const unsigned short* Wsd[4] = {Wall + 4096, Wall + 2 * 4096, Wall + 3 * 4096, Wall + 4 * 4096};
    const unsigned short* Wds[4] = {Wall + 5 * 4096, Wall + 6 * 4096, Wall + 7 * 4096, Wall + 8 * 4096};

    int spmmGrid = idiv(N * 64, 256);
    int mgGrid = 512;

    if (mega) {
        // A-chain: y0..y3
        k_spmm<<<spmmGrid, 256, 0, stream>>>(xb, bufA, rptr, adj, inv_r, N, idxbits);    // y0
        k_spmm<<<spmmGrid, 256, 0, stream>>>(bufA, bufB, rptr, adj, inv_r, N, idxbits);  // y1
        k_spmm<<<spmmGrid, 256, 0, stream>>>(bufB, bufC, rptr, adj, inv_r, N, idxbits);  // y2
        k_spmm<<<spmmGrid, 256, 0, stream>>>(bufC, bufD, rptr, adj, inv_r, N, idxbits);  // y3
        // z = s0 x Wds0^T + s1 y1 Wds1^T + s2 y2 Wds2^T + s3 y3 Wds3^T  (bf16)
        k_mg<4, true, true><<<mgGrid, 256, 0, stream>>>(
            xb, bufB, bufC, bufD, nullptr,
            Wds[0], Wds[1], Wds[2], Wds[3], nullptr, nullptr, zb, N);
        // out = cb + W0c x + s0 y0 Wsd0^T + ... + s3 y3 Wsd3^T  (fp32)
        k_mg<5, true, false><<<mgGrid, 256, 0, stream>>>(
            xb, bufA, bufB, bufC, bufD,
            W0c, Wsd[0], Wsd[1], Wsd[2], Wsd[3], cb, out, N);
        // out += A^T z
        k_spmm_acc<<<spmmGrid, 256, 0, stream>>>(zb, out, cptr, adjT, inv_c, N, idxbits);
    } else {
        // fallback: round-5 structure with 2 rotating buffers (8 SpMMs)
        k_spmm<<<spmmGrid, 256, 0, stream>>>(xb, bufA, rptr, adj, inv_r, N, idxbits);
        k_spmm<<<spmmGrid, 256, 0, stream>>>(xb, bufB, cptr, adjT, inv_c, N, idxbits);
        k_mg<3, true, false><<<mgGrid, 256, 0, stream>>>(
            xb, bufA, bufB, nullptr, nullptr,
            W0c, Wsd[0], Wds[0], nullptr, nullptr, cb, out, N);
        unsigned short* ycur = bufA;
        unsigned short* yfree = bufB;
        for (int i = 1; i < 4; i++) {
            k_spmm<<<spmmGrid, 256, 0, stream>>>(ycur, yfree, rptr, adj, inv_r, N, idxbits);
            k_spmm<<<spmmGrid, 256, 0, stream>>>(yfree, ycur, cptr, adjT, inv_c, N, idxbits);
            k_mg<2, false, false><<<mgGrid, 256, 0, stream>>>(
                yfree, ycur, nullptr, nullptr, nullptr,
                Wsd[i], Wds[i], nullptr, nullptr, nullptr, nullptr, out, N);
            unsigned short* t = ycur; ycur = yfree; yfree = t;
        }
    }
}

// Round 10
// 554.454 us; speedup vs baseline: 1.2827x; 1.2827x over previous
//
#include <hip/hip_runtime.h>
#include <hip/hip_bf16.h>

#define DIM 64
#define SCAN_CHUNK 2048
#define NCH 128        // edge chunks per side (LDS-histogram build)
#define HWORDS 32768   // 128 KB static LDS histogram

typedef __bf16 bf16v8 __attribute__((ext_vector_type(8)));
typedef float f32v4 __attribute__((ext_vector_type(4)));

static inline int idiv(int a, int b) { return (a + b - 1) / b; }

__device__ inline unsigned short f2b(float f) {
    __hip_bfloat16 h = __float2bfloat16(f);
    return *reinterpret_cast<unsigned short*>(&h);
}
__device__ inline float b2f(unsigned short u) {
    __hip_bfloat16 h;
    *reinterpret_cast<unsigned short*>(&h) = u;
    return __bfloat162float(h);
}

// ================= LDS byte-histogram CSR build (mega path) =================
// cnt layout: [2][NCH][N] bytes (row side then col side), aliased onto bufC+bufD.

// Phase 1: per-(chunk,node) counts; whole node range in byte-packed LDS.
__global__ __launch_bounds__(1024, 1) void k_hist1(const int* __restrict__ row,
                                                   const int* __restrict__ col,
                                                   unsigned char* __restrict__ cnt,
                                                   int E, int N, int C) {
    __shared__ int hsh[HWORDS];
    int b = blockIdx.x;              // 0..2*NCH-1
    int side = b >> 7;
    int lb = b & (NCH - 1);
    const int* key = side ? col : row;
    int words = (N + 3) >> 2;
    for (int i = threadIdx.x; i < words; i += blockDim.x) hsh[i] = 0;
    __syncthreads();
    int e0 = lb * C, e1 = min(e0 + C, E);
    for (int e = e0 + threadIdx.x; e < e1; e += blockDim.x) {
        int v = key[e];
        atomicAdd(&hsh[v >> 2], 1 << ((v & 3) * 8));
    }
    __syncthreads();
    int* my = (int*)(cnt + (size_t)b * N);   // N%4==0 guaranteed by host gate
    int nw = N >> 2;
    for (int i = threadIdx.x; i < nw; i += blockDim.x) my[i] = hsh[i];
}

// Phase 2: per-node exclusive prefix over the NCH chunks (byte offsets, in
// place) + total degree.
__global__ __launch_bounds__(256) void k_prefixB(unsigned char* __restrict__ cnt,
                                                 int* __restrict__ degs, int N) {
    int v = blockIdx.x * blockDim.x + threadIdx.x;
    if (v < 2 * N) {
        int side = (v >= N) ? 1 : 0;
        int node = v - side * N;
        unsigned char* p = cnt + (size_t)side * NCH * N + node;
        int s = 0;
#pragma unroll 8
        for (int b = 0; b < NCH; b++) {
            unsigned char c = p[(size_t)b * N];
            p[(size_t)b * N] = (unsigned char)s;
            s += c;
        }
        degs[v] = s;
    }
}

// Phase 3: replay histogram; old BYTE = unique within-(chunk,node) slot.
// Plain stores (r8: nt scatter regressed — L2 write-combining beats no-RFO).
__global__ __launch_bounds__(1024, 1) void k_fill3(const int* __restrict__ row,
        const int* __restrict__ col,
        const int* __restrict__ rptr, const int* __restrict__ cptr,
        const unsigned char* __restrict__ cnt,
        const int* __restrict__ deg_r, const int* __restrict__ deg_c,
        unsigned* __restrict__ adj, unsigned* __restrict__ adjT,
        int E, int N, int C, int idxbits) {
    __shared__ int hsh[HWORDS];
    int b = blockIdx.x;
    int side = b >> 7;
    int lb = b & (NCH - 1);
    const int* key = side ? col : row;
    const int* oth = side ? row : col;
    const int* ptr = side ? cptr : rptr;
    const int* odeg = side ? deg_r : deg_c;
    unsigned* dst = side ? adjT : adj;
    const unsigned char* my = cnt + (size_t)b * N;
    int words = (N + 3) >> 2;
    for (int i = threadIdx.x; i < words; i += blockDim.x) hsh[i] = 0;
    __syncthreads();
    unsigned dmask = (1u << (32 - idxbits)) - 1u;
    int e0 = lb * C, e1 = min(e0 + C, E);
    for (int e = e0 + threadIdx.x; e < e1; e += blockDim.x) {
        int v = key[e];
        int sh = (v & 3) * 8;
        unsigned old = (unsigned)atomicAdd(&hsh[v >> 2], 1 << sh);
        int slot = (int)((old >> sh) & 255u);
        int o = oth[e];
        unsigned d = min((unsigned)odeg[o], dmask);
        dst[ptr[v] + (int)my[v] + slot] = (unsigned)o | (d << idxbits);
    }
}

// ================= legacy atomic build (fallback path) =================
__global__ void k_degrees(const int* __restrict__ row, const int* __restrict__ col,
                          int* __restrict__ dr, int* __restrict__ dc,
                          unsigned* __restrict__ slot, int E) {
    int e = blockIdx.x * blockDim.x + threadIdx.x;
    if (e < E) {
        unsigned sr = (unsigned)atomicAdd(&dr[row[e]], 1);
        unsigned sc = (unsigned)atomicAdd(&dc[col[e]], 1);
        slot[e] = (sr & 0xFFFFu) | (sc << 16);
    }
}

__global__ void k_fill(const int* __restrict__ row, const int* __restrict__ col,
                       const int* __restrict__ rptr, const int* __restrict__ cptr,
                       const unsigned* __restrict__ slot,
                       const int* __restrict__ deg_r, const int* __restrict__ deg_c,
                       unsigned* __restrict__ adj, unsigned* __restrict__ adjT,
                       int E, int idxbits) {
    int e = blockIdx.x * blockDim.x + threadIdx.x;
    if (e < E) {
        int r = row[e], c = col[e];
        unsigned s = slot[e];
        unsigned sr = s & 0xFFFFu;
        unsigned sc = s >> 16;
        unsigned wmask = (1u << (32 - idxbits)) - 1u;
        unsigned wc = (unsigned)min((unsigned)deg_c[c], wmask);
        unsigned wr = (unsigned)min((unsigned)deg_r[r], wmask);
        adj [rptr[r] + sr] = (unsigned)c | (wc << idxbits);
        adjT[cptr[c] + sc] = (unsigned)r | (wr << idxbits);
    }
}

// ================= scans =================
__global__ __launch_bounds__(256) void k_scan_blk(const int* __restrict__ deg_r,
                                                  const int* __restrict__ deg_c,
                                                  int* __restrict__ part, int n, int G) {
    int b = blockIdx.x;
    const int* deg = (b < G) ? deg_r : deg_c;
    int lb = (b < G) ? b : b - G;
    int base = lb * SCAN_CHUNK;
    int t = threadIdx.x;
    int s = 0;
    for (int i = t; i < SCAN_CHUNK; i += 256) {
        int g = base + i;
        if (g < n) s += deg[g];
    }
    __shared__ int red[256];
    red[t] = s;
    __syncthreads();
    for (int off = 128; off > 0; off >>= 1) {
        if (t < off) red[t] += red[t + off];
        __syncthreads();
    }
    if (t == 0) part[b] = red[0];
}

__global__ __launch_bounds__(1024) void k_scan_top(int* __restrict__ part, int G,
        const float* __restrict__ bs_sd, const float* __restrict__ b0_sd,
        const float* __restrict__ bs_ds, const float* __restrict__ b0_ds,
        float* __restrict__ cb) {
    int t = threadIdx.x;
    if (blockIdx.x == 2) {
        if (t < 64) {
            float ssd = bs_sd[t] + b0_sd[t];
            float sds = bs_ds[t] + b0_ds[t];
            float sc = 1.f;
            for (int i = 1; i < 4; i++) {
                sc *= 0.5f;
                ssd += bs_sd[i * 64 + t] * sc;
                sds += bs_ds[i * 64 + t] * sc;
            }
            cb[t] = 0.5f * ssd + 0.5f * sds;  // ALPHA = 0.5
        }
        return;
    }
    int* p = part + ((blockIdx.x == 0) ? 0 : G);
    __shared__ int sums[1024];
    sums[t] = (t < G) ? p[t] : 0;
    __syncthreads();
    for (int off = 1; off < 1024; off <<= 1) {
        int v = (t >= off) ? sums[t - off] : 0;
        __syncthreads();
        sums[t] += v;
        __syncthreads();
    }
    if (t < G) p[t] = (t == 0) ? 0 : sums[t - 1];
}

__global__ __launch_bounds__(256) void k_scan_fin(const int* __restrict__ deg_r,
                                                  const int* __restrict__ deg_c,
                                                  const int* __restrict__ part,
                                                  int* __restrict__ rptr, int* __restrict__ cptr,
                                                  float* __restrict__ inv_r, float* __restrict__ inv_c,
                                                  int n, int G) {
    int b = blockIdx.x;
    bool isr = (b < G);
    const int* deg = isr ? deg_r : deg_c;
    int* ptr = isr ? rptr : cptr;
    float* inv = isr ? inv_r : inv_c;
    int lb = isr ? b : b - G;
    int off = part[b];
    int base = lb * SCAN_CHUNK;
    int t = threadIdx.x;
    int start = base + t * 8;
    int v[8];
    int s = 0;
#pragma unroll
    for (int k = 0; k < 8; k++) {
        int g = start + k;
        int d = (g < n) ? deg[g] : 0;
        v[k] = d;
        s += d;
    }
    __shared__ int sums[256];
    sums[t] = s;
    __syncthreads();
    for (int o = 1; o < 256; o <<= 1) {
        int x = (t >= o) ? sums[t - o] : 0;
        __syncthreads();
        sums[t] += x;
        __syncthreads();
    }
    int run = off + ((t == 0) ? 0 : sums[t - 1]);
#pragma unroll
    for (int k = 0; k < 8; k++) {
        int g = start + k;
        if (g < n) {
            ptr[g] = run;
            inv[g] = (v[k] > 0) ? rsqrtf((float)v[k]) : 0.f;
            run += v[k];
        }
    }
    if (t == 255 && lb == G - 1) ptr[n] = run;  // grand total
}

// ================= misc prep =================
__global__ void k_xcast(const float* __restrict__ x, unsigned short* __restrict__ xb, int total) {
    int i = (blockIdx.x * blockDim.x + threadIdx.x) * 4;
    if (i < total) {
        float4 v = *reinterpret_cast<const float4*>(x + i);
        ushort4 o;
        o.x = f2b(v.x); o.y = f2b(v.y); o.z = f2b(v.z); o.w = f2b(v.w);
        *reinterpret_cast<ushort4*>(xb + i) = o;
    }
}

__global__ void k_wprep(const float* __restrict__ Ws_sd, const float* __restrict__ Ws_ds,
                        const float* __restrict__ W0_sd, const float* __restrict__ W0_ds,
                        unsigned short* __restrict__ Wall) {
    int i = blockIdx.x * blockDim.x + threadIdx.x;  // 9*4096 total
    if (i >= 9 * 4096) return;
    int m = i >> 12, src = i & 4095;
    float v;
    if (m == 0) {
        v = 0.5f * (W0_sd[src] + W0_ds[src]);
    } else if (m < 5) {
        int hop = m - 1;
        v = Ws_sd[hop * 4096 + src] * (0.5f / (float)(1 << hop));
    } else {
        int hop = m - 5;
        v = Ws_ds[hop * 4096 + src] * (0.5f / (float)(1 << hop));
    }
    Wall[i] = f2b(v);
}

// ================= SpMM — dual-edge halves: each 32-lane half processes one
// edge, 4 B (2 bf16) per lane -> VMEM instrs per edge halved, 2x edges in
// flight. Cross-half combine via shfl_xor(32). =================
__global__ __launch_bounds__(256) void k_spmm(const unsigned short* __restrict__ h,
                                              unsigned short* __restrict__ out,
                                              const int* __restrict__ ptr,
                                              const unsigned* __restrict__ adj,
                                              const float* __restrict__ inv_self,
                                              int n, int idxbits) {
    int gw = (blockIdx.x * blockDim.x + threadIdx.x) >> 6;
    int lane = threadIdx.x & 63;
    if (gw >= n) return;
    int half = lane >> 5, m = lane & 31;
    int beg = ptr[gw], end = ptr[gw + 1];
    unsigned imask = (1u << idxbits) - 1u;
    float ax = 0.f, ay = 0.f;
#pragma unroll 4
    for (int j = beg + half; j < end; j += 2) {
        unsigned p = adj[j];
        float w = rsqrtf((float)(p >> idxbits));
        unsigned hv = *reinterpret_cast<const unsigned*>(
            h + (size_t)(p & imask) * DIM + 2 * m);
        ax = fmaf(w, b2f((unsigned short)(hv & 0xFFFFu)), ax);
        ay = fmaf(w, b2f((unsigned short)(hv >> 16)), ay);
    }
    ax += __shfl_xor(ax, 32);
    ay += __shfl_xor(ay, 32);
    if (half == 0) {
        float iv = inv_self[gw];
        ushort2 o;
        o.x = f2b(iv * ax);
        o.y = f2b(iv * ay);
        *reinterpret_cast<ushort2*>(out + (size_t)gw * DIM + 2 * m) = o;
    }
}

__global__ __launch_bounds__(256) void k_spmm_acc(const unsigned short* __restrict__ h,
                                                  float* __restrict__ out,
                                                  const int* __restrict__ ptr,
                                                  const unsigned* __restrict__ adj,
                                                  const float* __restrict__ inv_self,
                                                  int n, int idxbits) {
    int gw = (blockIdx.x * blockDim.x + threadIdx.x) >> 6;
    int lane = threadIdx.x & 63;
    if (gw >= n) return;
    int half = lane >> 5, m = lane & 31;
    int beg = ptr[gw], end = ptr[gw + 1];
    unsigned imask = (1u << idxbits) - 1u;
    float ax = 0.f, ay = 0.f;
#pragma unroll 4
    for (int j = beg + half; j < end; j += 2) {
        unsigned p = adj[j];
        float w = rsqrtf((float)(p >> idxbits));
        unsigned hv = *reinterpret_cast<const unsigned*>(
            h + (size_t)(p & imask) * DIM + 2 * m);
        ax = fmaf(w, b2f((unsigned short)(hv & 0xFFFFu)), ax);
        ay = fmaf(w, b2f((unsigned short)(hv >> 16)), ay);
    }
    ax += __shfl_xor(ax, 32);
    ay += __shfl_xor(ay, 32);
    if (half == 0) {
        float iv = inv_self[gw];
        float2* po = reinterpret_cast<float2*>(out + (size_t)gw * DIM + 2 * m);
        float2 v = *po;
        v.x += iv * ax;
        v.y += iv * ay;
        *po = v;
    }
}

// ================= multi-matrix MFMA GEMM =================
template <int NM, bool INIT, bool BF16OUT>
__global__ __launch_bounds__(256, 2) void k_mg(
        const unsigned short* __restrict__ h0, const unsigned short* __restrict__ h1,
        const unsigned short* __restrict__ h2, const unsigned short* __restrict__ h3,
        const unsigned short* __restrict__ h4,
        const unsigned short* __restrict__ W0, const unsigned short* __restrict__ W1,
        const unsigned short* __restrict__ W2, const unsigned short* __restrict__ W3,
        const unsigned short* __restrict__ W4,
        const float* __restrict__ cb, void* __restrict__ outv, int n) {
    const unsigned short* hs[5] = {h0, h1, h2, h3, h4};
    const unsigned short* Ws[5] = {W0, W1, W2, W3, W4};
    float* outf = (float*)outv;
    unsigned short* outb = (unsigned short*)outv;
    int lane = threadIdx.x & 63;
    int quad = lane >> 4;
    int l16 = lane & 15;
    int nmax = n - 1;

    bf16v8 w[NM][4][2];
#pragma unroll
    for (int m = 0; m < NM; m++)
#pragma unroll
        for (int ot = 0; ot < 4; ot++)
#pragma unroll
            for (int kh = 0; kh < 2; kh++)
                w[m][ot][kh] = *reinterpret_cast<const bf16v8*>(
                    Ws[m] + (size_t)(ot * 16 + l16) * 64 + kh * 32 + quad * 8);

    float bias[4];
    if (INIT) {
#pragma unroll
        for (int ot = 0; ot < 4; ot++) bias[ot] = cb ? cb[ot * 16 + l16] : 0.f;
    }
    int tiles_all = (n + 15) >> 4;
    int wave = (blockIdx.x * blockDim.x + threadIdx.x) >> 6;
    int nw = (gridDim.x * blockDim.x) >> 6;
    for (int t = wave; t < tiles_all; t += nw) {
        int row0 = t << 4;
        int arow = min(row0 + l16, nmax);
        bf16v8 a[NM][2];
#pragma unroll
        for (int m = 0; m < NM; m++) {
            const bf16v8* p = reinterpret_cast<const bf16v8*>(hs[m] + (size_t)arow * 64 + quad * 8);
            a[m][0] = p[0];
            a[m][1] = p[4];
        }
        f32v4 acc[4];
        if (INIT) {
#pragma unroll
            for (int ot = 0; ot < 4; ot++) {
                float b = bias[ot];
                acc[ot] = f32v4{b, b, b, b};
            }
        } else {
#pragma unroll
            for (int ot = 0; ot < 4; ot++)
#pragma unroll
                for (int r = 0; r < 4; r++)
                    acc[ot][r] = outf[(size_t)min(row0 + quad * 4 + r, nmax) * 64 + ot * 16 + l16];
        }
#pragma unroll
        for (int ot = 0; ot < 4; ot++)
#pragma unroll
            for (int m = 0; m < NM; m++) {
                acc[ot] = __builtin_amdgcn_mfma_f32_16x16x32_bf16(a[m][0], w[m][ot][0], acc[ot], 0, 0, 0);
                acc[ot] = __builtin_amdgcn_mfma_f32_16x16x32_bf16(a[m][1], w[m][ot][1], acc[ot], 0, 0, 0);
            }
#pragma unroll
        for (int ot = 0; ot < 4; ot++)
#pragma unroll
            for (int r = 0; r < 4; r++) {
                int rr = row0 + quad * 4 + r;
                if (rr < n) {
                    if (BF16OUT) outb[(size_t)rr * 64 + ot * 16 + l16] = f2b(acc[ot][r]);
                    else         outf[(size_t)rr * 64 + ot * 16 + l16] = acc[ot][r];
                }
            }
    }
}

extern "C" void kernel_launch(void* const* d_in, const int* in_sizes, int n_in,
                              void* d_out, int out_size, void* d_ws, size_t ws_size,
                              hipStream_t stream) {
    const float* x     = (const float*)d_in[0];
    const int*   ei    = (const int*)d_in[1];
    const float* Ws_sd = (const float*)d_in[2];
    const float* bs_sd = (const float*)d_in[3];
    const float* Ws_ds = (const float*)d_in[4];
    const float* bs_ds = (const float*)d_in[5];
    const float* W0_sd = (const float*)d_in[6];
    const float* b0_sd = (const float*)d_in[7];
    const float* W0_ds = (const float*)d_in[8];
    const float* b0_ds = (const float*)d_in[9];

    int N = in_sizes[0] / DIM;
    int E = in_sizes[1] / 2;
    const int* row = ei;
    const int* col = ei + E;
    float* out = (float*)d_out;

    int G = idiv(N, SCAN_CHUNK);
    int idxbits = 1;
    while ((1 << idxbits) < N) idxbits++;

    char* wsp = (char*)d_ws;
    auto alloc = [&](size_t bytes) -> void* {
        void* p = (void*)wsp;
        wsp += ((bytes + 63) / 64) * 64;
        return p;
    };
    size_t bufBytes = ((((size_t)N * DIM * 2) + 63) / 64) * 64;

    int* degs   = (int*)alloc((size_t)2 * N * 4);
    int* deg_r  = degs;
    int* deg_c  = degs + N;
    int* rptr   = (int*)alloc(((size_t)N + 1) * 4);
    int* cptr   = (int*)alloc(((size_t)N + 1) * 4);
    unsigned* adj  = (unsigned*)alloc((size_t)E * 4);
    unsigned* adjT = (unsigned*)alloc((size_t)E * 4);
    unsigned short* xb = (unsigned short*)alloc((size_t)N * DIM * 2);
    float* invs = (float*)alloc((size_t)2 * N * 4);
    float* inv_r = invs;
    float* inv_c = invs + N;
    float* cb   = (float*)alloc(64 * 4);
    unsigned short* Wall = (unsigned short*)alloc((size_t)9 * 4096 * 2);
    int* part   = (int*)alloc((size_t)2 * G * 4);
    unsigned* slot = (unsigned*)alloc((size_t)E * 4);   // fallback path only
    unsigned short* zb = (unsigned short*)alloc((size_t)N * DIM * 2);

    size_t fixed_used = (size_t)(wsp - (char*)d_ws);
    bool mega = (fixed_used + 4 * bufBytes) <= ws_size;

    unsigned short* bufA = (unsigned short*)alloc((size_t)N * DIM * 2);
    unsigned short* bufB = (unsigned short*)alloc((size_t)N * DIM * 2);
    unsigned short* bufC = mega ? (unsigned short*)alloc((size_t)N * DIM * 2) : nullptr;
    unsigned short* bufD = mega ? (unsigned short*)alloc((size_t)N * DIM * 2) : nullptr;

    // cnt [2][NCH][N] bytes = 256N aliases bufC+bufD (= 2*128N bytes, exact fit);
    // consumed by k_fill3 before y2/y3 first write bufC/bufD.
    unsigned char* cnt = (unsigned char*)bufC;
    bool ldsb = mega && (N <= HWORDS * 4) && ((N & 3) == 0);
    int C = idiv(E, NCH);

    if (ldsb) {
        k_hist1<<<2 * NCH, 1024, 0, stream>>>(row, col, cnt, E, N, C);
        k_prefixB<<<idiv(2 * N, 256), 256, 0, stream>>>(cnt, degs, N);
    } else {
        hipMemsetAsync(degs, 0, (size_t)2 * N * sizeof(int), stream);
        k_degrees<<<idiv(E, 256), 256, 0, stream>>>(row, col, deg_r, deg_c, slot, E);
    }
    k_scan_blk<<<2 * G, 256, 0, stream>>>(deg_r, deg_c, part, N, G);
    k_scan_top<<<3, 1024, 0, stream>>>(part, G, bs_sd, b0_sd, bs_ds, b0_ds, cb);
    k_scan_fin<<<2 * G, 256, 0, stream>>>(deg_r, deg_c, part, rptr, cptr, inv_r, inv_c, N, G);
    if (ldsb) {
        k_fill3<<<2 * NCH, 1024, 0, stream>>>(row, col, rptr, cptr, cnt,
                                              deg_r, deg_c, adj, adjT, E, N, C, idxbits);
    } else {
        k_fill<<<idiv(E, 256), 256, 0, stream>>>(row, col, rptr, cptr, slot,
                                                 deg_r, deg_c, adj, adjT, E, idxbits);
    }
    k_xcast<<<idiv(N * DIM / 4, 256), 256, 0, stream>>>(x, xb, N * DIM);
    k_wprep<<<144, 256, 0, stream>>>(Ws_sd, Ws_ds, W0_sd, W0_ds, Wall);

    const unsigned short* W0c = Wall;
    const unsigned short* Wsd[4] = {Wall + 4096, Wall + 2 * 4096, Wall + 3 * 4096, Wall + 4 * 4096};
    const unsigned short* Wds[4] = {Wall + 5 * 4096, Wall + 6 * 4096, Wall + 7 * 4096, Wall + 8 * 4096};

    int spmmGrid = idiv(N * 64, 256);
    int mgGrid = 512;

    if (mega) {
        // A-chain: y0..y3
        k_spmm<<<spmmGrid, 256, 0, stream>>>(xb, bufA, rptr, adj, inv_r, N, idxbits);    // y0
        k_spmm<<<spmmGrid, 256, 0, stream>>>(bufA, bufB, rptr, adj, inv_r, N, idxbits);  // y1
        k_spmm<<<spmmGrid, 256, 0, stream>>>(bufB, bufC, rptr, adj, inv_r, N, idxbits);  // y2
        k_spmm<<<spmmGrid, 256, 0, stream>>>(bufC, bufD, rptr, adj, inv_r, N, idxbits);  // y3
        // z = s0 x Wds0^T + s1 y1 Wds1^T + s2 y2 Wds2^T + s3 y3 Wds3^T  (bf16)
        k_mg<4, true, true><<<mgGrid, 256, 0, stream>>>(
            xb, bufB, bufC, bufD, nullptr,
            Wds[0], Wds[1], Wds[2], Wds[3], nullptr, nullptr, zb, N);
        // out = cb + W0c x + s0 y0 Wsd0^T + ... + s3 y3 Wsd3^T  (fp32)
        k_mg<5, true, false><<<mgGrid, 256, 0, stream>>>(
            xb, bufA, bufB, bufC, bufD,
            W0c, Wsd[0], Wsd[1], Wsd[2], Wsd[3], cb, out, N);
        // out += A^T z
        k_spmm_acc<<<spmmGrid, 256, 0, stream>>>(zb, out, cptr, adjT, inv_c, N, idxbits);
    } else {
        // fallback: round-5 structure with 2 rotating buffers (8 SpMMs)
        k_spmm<<<spmmGrid, 256, 0, stream>>>(xb, bufA, rptr, adj, inv_r, N, idxbits);
        k_spmm<<<spmmGrid, 256, 0, stream>>>(xb, bufB, cptr, adjT, inv_c, N, idxbits);
        k_mg<3, true, false><<<mgGrid, 256, 0, stream>>>(
            xb, bufA, bufB, nullptr, nullptr,
            W0c, Wsd[0], Wds[0], nullptr, nullptr, cb, out, N);
        unsigned short* ycur = bufA;
        unsigned short* yfree = bufB;
        for (int i = 1; i < 4; i++) {
            k_spmm<<<spmmGrid, 256, 0, stream>>>(ycur, yfree, rptr, adj, inv_r, N, idxbits);
            k_spmm<<<spmmGrid, 256, 0, stream>>>(yfree, ycur, cptr, adjT, inv_c, N, idxbits);
            k_mg<2, false, false><<<mgGrid, 256, 0, stream>>>(
                yfree, ycur, nullptr, nullptr, nullptr,
                Wsd[i], Wds[i], nullptr, nullptr, nullptr, nullptr, out, N);
            unsigned short* t = ycur; ycur = yfree; yfree = t;
        }
    }
}

// Round 11
// 531.377 us; speedup vs baseline: 1.3384x; 1.0434x over previous
//
#include <hip/hip_runtime.h>
#include <hip/hip_bf16.h>

#define DIM 64
#define SCAN_CHUNK 2048
#define NCH 128        // edge chunks per side (LDS-histogram build)
#define HWORDS 32768   // 128 KB static LDS histogram

typedef __bf16 bf16v8 __attribute__((ext_vector_type(8)));
typedef float f32v4 __attribute__((ext_vector_type(4)));

static inline int idiv(int a, int b) { return (a + b - 1) / b; }

__device__ inline unsigned short f2b(float f) {
    __hip_bfloat16 h = __float2bfloat16(f);
    return *reinterpret_cast<unsigned short*>(&h);
}
__device__ inline float b2f(unsigned short u) {
    __hip_bfloat16 h;
    *reinterpret_cast<unsigned short*>(&h) = u;
    return __bfloat162float(h);
}

// ================= LDS byte-histogram CSR build (mega path) =================
// cnt layout: [2][NCH][N] bytes (row side then col side), aliased onto bufC+bufD.

// Phase 1: per-(chunk,node) counts; whole node range in byte-packed LDS.
__global__ __launch_bounds__(1024, 1) void k_hist1(const int* __restrict__ row,
                                                   const int* __restrict__ col,
                                                   unsigned char* __restrict__ cnt,
                                                   int E, int N, int C) {
    __shared__ int hsh[HWORDS];
    int b = blockIdx.x;              // 0..2*NCH-1
    int side = b >> 7;
    int lb = b & (NCH - 1);
    const int* key = side ? col : row;
    int words = (N + 3) >> 2;
    for (int i = threadIdx.x; i < words; i += blockDim.x) hsh[i] = 0;
    __syncthreads();
    int e0 = lb * C, e1 = min(e0 + C, E);
    for (int e = e0 + threadIdx.x; e < e1; e += blockDim.x) {
        int v = key[e];
        atomicAdd(&hsh[v >> 2], 1 << ((v & 3) * 8));
    }
    __syncthreads();
    int* my = (int*)(cnt + (size_t)b * N);   // N%4==0 guaranteed by host gate
    int nw = N >> 2;
    for (int i = threadIdx.x; i < nw; i += blockDim.x) my[i] = hsh[i];
}

// Phase 2: per-node exclusive prefix over the NCH chunks (byte offsets, in
// place) + total degree.
__global__ __launch_bounds__(256) void k_prefixB(unsigned char* __restrict__ cnt,
                                                 int* __restrict__ degs, int N) {
    int v = blockIdx.x * blockDim.x + threadIdx.x;
    if (v < 2 * N) {
        int side = (v >= N) ? 1 : 0;
        int node = v - side * N;
        unsigned char* p = cnt + (size_t)side * NCH * N + node;
        int s = 0;
#pragma unroll 8
        for (int b = 0; b < NCH; b++) {
            unsigned char c = p[(size_t)b * N];
            p[(size_t)b * N] = (unsigned char)s;
            s += c;
        }
        degs[v] = s;
    }
}

// Phase 3: replay histogram; old BYTE = unique within-(chunk,node) slot.
// Plain stores (r8: nt scatter regressed — L2 write-combining beats no-RFO).
__global__ __launch_bounds__(1024, 1) void k_fill3(const int* __restrict__ row,
        const int* __restrict__ col,
        const int* __restrict__ rptr, const int* __restrict__ cptr,
        const unsigned char* __restrict__ cnt,
        const int* __restrict__ deg_r, const int* __restrict__ deg_c,
        unsigned* __restrict__ adj, unsigned* __restrict__ adjT,
        int E, int N, int C, int idxbits) {
    __shared__ int hsh[HWORDS];
    int b = blockIdx.x;
    int side = b >> 7;
    int lb = b & (NCH - 1);
    const int* key = side ? col : row;
    const int* oth = side ? row : col;
    const int* ptr = side ? cptr : rptr;
    const int* odeg = side ? deg_r : deg_c;
    unsigned* dst = side ? adjT : adj;
    const unsigned char* my = cnt + (size_t)b * N;
    int words = (N + 3) >> 2;
    for (int i = threadIdx.x; i < words; i += blockDim.x) hsh[i] = 0;
    __syncthreads();
    unsigned dmask = (1u << (32 - idxbits)) - 1u;
    int e0 = lb * C, e1 = min(e0 + C, E);
    for (int e = e0 + threadIdx.x; e < e1; e += blockDim.x) {
        int v = key[e];
        int sh = (v & 3) * 8;
        unsigned old = (unsigned)atomicAdd(&hsh[v >> 2], 1 << sh);
        int slot = (int)((old >> sh) & 255u);
        int o = oth[e];
        unsigned d = min((unsigned)odeg[o], dmask);
        dst[ptr[v] + (int)my[v] + slot] = (unsigned)o | (d << idxbits);
    }
}

// ================= legacy atomic build (fallback path) =================
__global__ void k_degrees(const int* __restrict__ row, const int* __restrict__ col,
                          int* __restrict__ dr, int* __restrict__ dc,
                          unsigned* __restrict__ slot, int E) {
    int e = blockIdx.x * blockDim.x + threadIdx.x;
    if (e < E) {
        unsigned sr = (unsigned)atomicAdd(&dr[row[e]], 1);
        unsigned sc = (unsigned)atomicAdd(&dc[col[e]], 1);
        slot[e] = (sr & 0xFFFFu) | (sc << 16);
    }
}

__global__ void k_fill(const int* __restrict__ row, const int* __restrict__ col,
                       const int* __restrict__ rptr, const int* __restrict__ cptr,
                       const unsigned* __restrict__ slot,
                       const int* __restrict__ deg_r, const int* __restrict__ deg_c,
                       unsigned* __restrict__ adj, unsigned* __restrict__ adjT,
                       int E, int idxbits) {
    int e = blockIdx.x * blockDim.x + threadIdx.x;
    if (e < E) {
        int r = row[e], c = col[e];
        unsigned s = slot[e];
        unsigned sr = s & 0xFFFFu;
        unsigned sc = s >> 16;
        unsigned wmask = (1u << (32 - idxbits)) - 1u;
        unsigned wc = (unsigned)min((unsigned)deg_c[c], wmask);
        unsigned wr = (unsigned)min((unsigned)deg_r[r], wmask);
        adj [rptr[r] + sr] = (unsigned)c | (wc << idxbits);
        adjT[cptr[c] + sc] = (unsigned)r | (wr << idxbits);
    }
}

// ================= scans =================
__global__ __launch_bounds__(256) void k_scan_blk(const int* __restrict__ deg_r,
                                                  const int* __restrict__ deg_c,
                                                  int* __restrict__ part, int n, int G) {
    int b = blockIdx.x;
    const int* deg = (b < G) ? deg_r : deg_c;
    int lb = (b < G) ? b : b - G;
    int base = lb * SCAN_CHUNK;
    int t = threadIdx.x;
    int s = 0;
    for (int i = t; i < SCAN_CHUNK; i += 256) {
        int g = base + i;
        if (g < n) s += deg[g];
    }
    __shared__ int red[256];
    red[t] = s;
    __syncthreads();
    for (int off = 128; off > 0; off >>= 1) {
        if (t < off) red[t] += red[t + off];
        __syncthreads();
    }
    if (t == 0) part[b] = red[0];
}

__global__ __launch_bounds__(1024) void k_scan_top(int* __restrict__ part, int G,
        const float* __restrict__ bs_sd, const float* __restrict__ b0_sd,
        const float* __restrict__ bs_ds, const float* __restrict__ b0_ds,
        float* __restrict__ cb) {
    int t = threadIdx.x;
    if (blockIdx.x == 2) {
        if (t < 64) {
            float ssd = bs_sd[t] + b0_sd[t];
            float sds = bs_ds[t] + b0_ds[t];
            float sc = 1.f;
            for (int i = 1; i < 4; i++) {
                sc *= 0.5f;
                ssd += bs_sd[i * 64 + t] * sc;
                sds += bs_ds[i * 64 + t] * sc;
            }
            cb[t] = 0.5f * ssd + 0.5f * sds;  // ALPHA = 0.5
        }
        return;
    }
    int* p = part + ((blockIdx.x == 0) ? 0 : G);
    __shared__ int sums[1024];
    sums[t] = (t < G) ? p[t] : 0;
    __syncthreads();
    for (int off = 1; off < 1024; off <<= 1) {
        int v = (t >= off) ? sums[t - off] : 0;
        __syncthreads();
        sums[t] += v;
        __syncthreads();
    }
    if (t < G) p[t] = (t == 0) ? 0 : sums[t - 1];
}

__global__ __launch_bounds__(256) void k_scan_fin(const int* __restrict__ deg_r,
                                                  const int* __restrict__ deg_c,
                                                  const int* __restrict__ part,
                                                  int* __restrict__ rptr, int* __restrict__ cptr,
                                                  float* __restrict__ inv_r, float* __restrict__ inv_c,
                                                  int n, int G) {
    int b = blockIdx.x;
    bool isr = (b < G);
    const int* deg = isr ? deg_r : deg_c;
    int* ptr = isr ? rptr : cptr;
    float* inv = isr ? inv_r : inv_c;
    int lb = isr ? b : b - G;
    int off = part[b];
    int base = lb * SCAN_CHUNK;
    int t = threadIdx.x;
    int start = base + t * 8;
    int v[8];
    int s = 0;
#pragma unroll
    for (int k = 0; k < 8; k++) {
        int g = start + k;
        int d = (g < n) ? deg[g] : 0;
        v[k] = d;
        s += d;
    }
    __shared__ int sums[256];
    sums[t] = s;
    __syncthreads();
    for (int o = 1; o < 256; o <<= 1) {
        int x = (t >= o) ? sums[t - o] : 0;
        __syncthreads();
        sums[t] += x;
        __syncthreads();
    }
    int run = off + ((t == 0) ? 0 : sums[t - 1]);
#pragma unroll
    for (int k = 0; k < 8; k++) {
        int g = start + k;
        if (g < n) {
            ptr[g] = run;
            inv[g] = (v[k] > 0) ? rsqrtf((float)v[k]) : 0.f;
            run += v[k];
        }
    }
    if (t == 255 && lb == G - 1) ptr[n] = run;  // grand total
}

// ================= misc prep =================
__global__ void k_xcast(const float* __restrict__ x, unsigned short* __restrict__ xb, int total) {
    int i = (blockIdx.x * blockDim.x + threadIdx.x) * 4;
    if (i < total) {
        float4 v = *reinterpret_cast<const float4*>(x + i);
        ushort4 o;
        o.x = f2b(v.x); o.y = f2b(v.y); o.z = f2b(v.z); o.w = f2b(v.w);
        *reinterpret_cast<ushort4*>(xb + i) = o;
    }
}

__global__ void k_wprep(const float* __restrict__ Ws_sd, const float* __restrict__ Ws_ds,
                        const float* __restrict__ W0_sd, const float* __restrict__ W0_ds,
                        unsigned short* __restrict__ Wall) {
    int i = blockIdx.x * blockDim.x + threadIdx.x;  // 9*4096 total
    if (i >= 9 * 4096) return;
    int m = i >> 12, src = i & 4095;
    float v;
    if (m == 0) {
        v = 0.5f * (W0_sd[src] + W0_ds[src]);
    } else if (m < 5) {
        int hop = m - 1;
        v = Ws_sd[hop * 4096 + src] * (0.5f / (float)(1 << hop));
    } else {
        int hop = m - 5;
        v = Ws_ds[hop * 4096 + src] * (0.5f / (float)(1 << hop));
    }
    Wall[i] = f2b(v);
}

// ================= SpMM — quad-edge groups: each 16-lane group processes one
// edge, 8 B (4 bf16) per lane (coalescing sweet spot) -> VMEM instrs per edge
// halved again vs dual-edge, 4 edges in flight. Combine via shfl_xor(32,16).
__global__ __launch_bounds__(256) void k_spmm(const unsigned short* __restrict__ h,
                                              unsigned short* __restrict__ out,
                                              const int* __restrict__ ptr,
                                              const unsigned* __restrict__ adj,
                                              const float* __restrict__ inv_self,
                                              int n, int idxbits) {
    int gw = (blockIdx.x * blockDim.x + threadIdx.x) >> 6;
    int lane = threadIdx.x & 63;
    if (gw >= n) return;
    int grp = lane >> 4, m = lane & 15;
    int beg = ptr[gw], end = ptr[gw + 1];
    unsigned imask = (1u << idxbits) - 1u;
    float a0 = 0.f, a1 = 0.f, a2 = 0.f, a3 = 0.f;
#pragma unroll 2
    for (int j = beg + grp; j < end; j += 4) {
        unsigned p = adj[j];
        float w = rsqrtf((float)(p >> idxbits));
        uint2 hv = *reinterpret_cast<const uint2*>(
            h + (size_t)(p & imask) * DIM + 4 * m);
        a0 = fmaf(w, b2f((unsigned short)(hv.x & 0xFFFFu)), a0);
        a1 = fmaf(w, b2f((unsigned short)(hv.x >> 16)), a1);
        a2 = fmaf(w, b2f((unsigned short)(hv.y & 0xFFFFu)), a2);
        a3 = fmaf(w, b2f((unsigned short)(hv.y >> 16)), a3);
    }
    a0 += __shfl_xor(a0, 32); a0 += __shfl_xor(a0, 16);
    a1 += __shfl_xor(a1, 32); a1 += __shfl_xor(a1, 16);
    a2 += __shfl_xor(a2, 32); a2 += __shfl_xor(a2, 16);
    a3 += __shfl_xor(a3, 32); a3 += __shfl_xor(a3, 16);
    if (grp == 0) {
        float iv = inv_self[gw];
        ushort4 o;
        o.x = f2b(iv * a0); o.y = f2b(iv * a1);
        o.z = f2b(iv * a2); o.w = f2b(iv * a3);
        *reinterpret_cast<ushort4*>(out + (size_t)gw * DIM + 4 * m) = o;
    }
}

__global__ __launch_bounds__(256) void k_spmm_acc(const unsigned short* __restrict__ h,
                                                  float* __restrict__ out,
                                                  const int* __restrict__ ptr,
                                                  const unsigned* __restrict__ adj,
                                                  const float* __restrict__ inv_self,
                                                  int n, int idxbits) {
    int gw = (blockIdx.x * blockDim.x + threadIdx.x) >> 6;
    int lane = threadIdx.x & 63;
    if (gw >= n) return;
    int grp = lane >> 4, m = lane & 15;
    int beg = ptr[gw], end = ptr[gw + 1];
    unsigned imask = (1u << idxbits) - 1u;
    float a0 = 0.f, a1 = 0.f, a2 = 0.f, a3 = 0.f;
#pragma unroll 2
    for (int j = beg + grp; j < end; j += 4) {
        unsigned p = adj[j];
        float w = rsqrtf((float)(p >> idxbits));
        uint2 hv = *reinterpret_cast<const uint2*>(
            h + (size_t)(p & imask) * DIM + 4 * m);
        a0 = fmaf(w, b2f((unsigned short)(hv.x & 0xFFFFu)), a0);
        a1 = fmaf(w, b2f((unsigned short)(hv.x >> 16)), a1);
        a2 = fmaf(w, b2f((unsigned short)(hv.y & 0xFFFFu)), a2);
        a3 = fmaf(w, b2f((unsigned short)(hv.y >> 16)), a3);
    }
    a0 += __shfl_xor(a0, 32); a0 += __shfl_xor(a0, 16);
    a1 += __shfl_xor(a1, 32); a1 += __shfl_xor(a1, 16);
    a2 += __shfl_xor(a2, 32); a2 += __shfl_xor(a2, 16);
    a3 += __shfl_xor(a3, 32); a3 += __shfl_xor(a3, 16);
    if (grp == 0) {
        float iv = inv_self[gw];
        float4* po = reinterpret_cast<float4*>(out + (size_t)gw * DIM + 4 * m);
        float4 v = *po;
        v.x += iv * a0; v.y += iv * a1;
        v.z += iv * a2; v.w += iv * a3;
        *po = v;
    }
}

// ================= multi-matrix MFMA GEMM =================
template <int NM, bool INIT, bool BF16OUT>
__global__ __launch_bounds__(256, 2) void k_mg(
        const unsigned short* __restrict__ h0, const unsigned short* __restrict__ h1,
        const unsigned short* __restrict__ h2, const unsigned short* __restrict__ h3,
        const unsigned short* __restrict__ h4,
        const unsigned short* __restrict__ W0, const unsigned short* __restrict__ W1,
        const unsigned short* __restrict__ W2, const unsigned short* __restrict__ W3,
        const unsigned short* __restrict__ W4,
        const float* __restrict__ cb, void* __restrict__ outv, int n) {
    const unsigned short* hs[5] = {h0, h1, h2, h3, h4};
    const unsigned short* Ws[5] = {W0, W1, W2, W3, W4};
    float* outf = (float*)outv;
    unsigned short* outb = (unsigned short*)outv;
    int lane = threadIdx.x & 63;
    int quad = lane >> 4;
    int l16 = lane & 15;
    int nmax = n - 1;

    bf16v8 w[NM][4][2];
#pragma unroll
    for (int m = 0; m < NM; m++)
#pragma unroll
        for (int ot = 0; ot < 4; ot++)
#pragma unroll
            for (int kh = 0; kh < 2; kh++)
                w[m][ot][kh] = *reinterpret_cast<const bf16v8*>(
                    Ws[m] + (size_t)(ot * 16 + l16) * 64 + kh * 32 + quad * 8);

    float bias[4];
    if (INIT) {
#pragma unroll
        for (int ot = 0; ot < 4; ot++) bias[ot] = cb ? cb[ot * 16 + l16] : 0.f;
    }
    int tiles_all = (n + 15) >> 4;
    int wave = (blockIdx.x * blockDim.x + threadIdx.x) >> 6;
    int nw = (gridDim.x * blockDim.x) >> 6;
    for (int t = wave; t < tiles_all; t += nw) {
        int row0 = t << 4;
        int arow = min(row0 + l16, nmax);
        bf16v8 a[NM][2];
#pragma unroll
        for (int m = 0; m < NM; m++) {
            const bf16v8* p = reinterpret_cast<const bf16v8*>(hs[m] + (size_t)arow * 64 + quad * 8);
            a[m][0] = p[0];
            a[m][1] = p[4];
        }
        f32v4 acc[4];
        if (INIT) {
#pragma unroll
            for (int ot = 0; ot < 4; ot++) {
                float b = bias[ot];
                acc[ot] = f32v4{b, b, b, b};
            }
        } else {
#pragma unroll
            for (int ot = 0; ot < 4; ot++)
#pragma unroll
                for (int r = 0; r < 4; r++)
                    acc[ot][r] = outf[(size_t)min(row0 + quad * 4 + r, nmax) * 64 + ot * 16 + l16];
        }
#pragma unroll
        for (int ot = 0; ot < 4; ot++)
#pragma unroll
            for (int m = 0; m < NM; m++) {
                acc[ot] = __builtin_amdgcn_mfma_f32_16x16x32_bf16(a[m][0], w[m][ot][0], acc[ot], 0, 0, 0);
                acc[ot] = __builtin_amdgcn_mfma_f32_16x16x32_bf16(a[m][1], w[m][ot][1], acc[ot], 0, 0, 0);
            }
#pragma unroll
        for (int ot = 0; ot < 4; ot++)
#pragma unroll
            for (int r = 0; r < 4; r++) {
                int rr = row0 + quad * 4 + r;
                if (rr < n) {
                    if (BF16OUT) outb[(size_t)rr * 64 + ot * 16 + l16] = f2b(acc[ot][r]);
                    else         outf[(size_t)rr * 64 + ot * 16 + l16] = acc[ot][r];
                }
            }
    }
}

extern "C" void kernel_launch(void* const* d_in, const int* in_sizes, int n_in,
                              void* d_out, int out_size, void* d_ws, size_t ws_size,
                              hipStream_t stream) {
    const float* x     = (const float*)d_in[0];
    const int*   ei    = (const int*)d_in[1];
    const float* Ws_sd = (const float*)d_in[2];
    const float* bs_sd = (const float*)d_in[3];
    const float* Ws_ds = (const float*)d_in[4];
    const float* bs_ds = (const float*)d_in[5];
    const float* W0_sd = (const float*)d_in[6];
    const float* b0_sd = (const float*)d_in[7];
    const float* W0_ds = (const float*)d_in[8];
    const float* b0_ds = (const float*)d_in[9];

    int N = in_sizes[0] / DIM;
    int E = in_sizes[1] / 2;
    const int* row = ei;
    const int* col = ei + E;
    float* out = (float*)d_out;

    int G = idiv(N, SCAN_CHUNK);
    int idxbits = 1;
    while ((1 << idxbits) < N) idxbits++;

    char* wsp = (char*)d_ws;
    auto alloc = [&](size_t bytes) -> void* {
        void* p = (void*)wsp;
        wsp += ((bytes + 63) / 64) * 64;
        return p;
    };
    size_t bufBytes = ((((size_t)N * DIM * 2) + 63) / 64) * 64;

    int* degs   = (int*)alloc((size_t)2 * N * 4);
    int* deg_r  = degs;
    int* deg_c  = degs + N;
    int* rptr   = (int*)alloc(((size_t)N + 1) * 4);
    int* cptr   = (int*)alloc(((size_t)N + 1) * 4);
    unsigned* adj  = (unsigned*)alloc((size_t)E * 4);
    unsigned* adjT = (unsigned*)alloc((size_t)E * 4);
    unsigned short* xb = (unsigned short*)alloc((size_t)N * DIM * 2);
    float* invs = (float*)alloc((size_t)2 * N * 4);
    float* inv_r = invs;
    float* inv_c = invs + N;
    float* cb   = (float*)alloc(64 * 4);
    unsigned short* Wall = (unsigned short*)alloc((size_t)9 * 4096 * 2);
    int* part   = (int*)alloc((size_t)2 * G * 4);
    unsigned* slot = (unsigned*)alloc((size_t)E * 4);   // fallback path only
    unsigned short* zb = (unsigned short*)alloc((size_t)N * DIM * 2);

    size_t fixed_used = (size_t)(wsp - (char*)d_ws);
    bool mega = (fixed_used + 4 * bufBytes) <= ws_size;

    unsigned short* bufA = (unsigned short*)alloc((size_t)N * DIM * 2);
    unsigned short* bufB = (unsigned short*)alloc((size_t)N * DIM * 2);
    unsigned short* bufC = mega ? (unsigned short*)alloc((size_t)N * DIM * 2) : nullptr;
    unsigned short* bufD = mega ? (unsigned short*)alloc((size_t)N * DIM * 2) : nullptr;

    // cnt [2][NCH][N] bytes = 256N aliases bufC+bufD (= 2*128N bytes, exact fit);
    // consumed by k_fill3 before y2/y3 first write bufC/bufD.
    unsigned char* cnt = (unsigned char*)bufC;
    bool ldsb = mega && (N <= HWORDS * 4) && ((N & 3) == 0);
    int C = idiv(E, NCH);

    if (ldsb) {
        k_hist1<<<2 * NCH, 1024, 0, stream>>>(row, col, cnt, E, N, C);
        k_prefixB<<<idiv(2 * N, 256), 256, 0, stream>>>(cnt, degs, N);
    } else {
        hipMemsetAsync(degs, 0, (size_t)2 * N * sizeof(int), stream);
        k_degrees<<<idiv(E, 256), 256, 0, stream>>>(row, col, deg_r, deg_c, slot, E);
    }
    k_scan_blk<<<2 * G, 256, 0, stream>>>(deg_r, deg_c, part, N, G);
    k_scan_top<<<3, 1024, 0, stream>>>(part, G, bs_sd, b0_sd, bs_ds, b0_ds, cb);
    k_scan_fin<<<2 * G, 256, 0, stream>>>(deg_r, deg_c, part, rptr, cptr, inv_r, inv_c, N, G);
    if (ldsb) {
        k_fill3<<<2 * NCH, 1024, 0, stream>>>(row, col, rptr, cptr, cnt,
                                              deg_r, deg_c, adj, adjT, E, N, C, idxbits);
    } else {
        k_fill<<<idiv(E, 256), 256, 0, stream>>>(row, col, rptr, cptr, slot,
                                                 deg_r, deg_c, adj, adjT, E, idxbits);
    }
    k_xcast<<<idiv(N * DIM / 4, 256), 256, 0, stream>>>(x, xb, N * DIM);
    k_wprep<<<144, 256, 0, stream>>>(Ws_sd, Ws_ds, W0_sd, W0_ds, Wall);

    const unsigned short* W0c = Wall;
    const unsigned short* Wsd[4] = {Wall + 4096, Wall + 2 * 4096, Wall + 3 * 4096, Wall + 4 * 4096};
    const unsigned short* Wds[4] = {Wall + 5 * 4096, Wall + 6 * 4096, Wall + 7 * 4096, Wall + 8 * 4096};

    int spmmGrid = idiv(N * 64, 256);
    int mgGrid = 512;

    if (mega) {
        // A-chain: y0..y3
        k_spmm<<<spmmGrid, 256, 0, stream>>>(xb, bufA, rptr, adj, inv_r, N, idxbits);    // y0
        k_spmm<<<spmmGrid, 256, 0, stream>>>(bufA, bufB, rptr, adj, inv_r, N, idxbits);  // y1
        k_spmm<<<spmmGrid, 256, 0, stream>>>(bufB, bufC, rptr, adj, inv_r, N, idxbits);  // y2
        k_spmm<<<spmmGrid, 256, 0, stream>>>(bufC, bufD, rptr, adj, inv_r, N, idxbits);  // y3
        // z = s0 x Wds0^T + s1 y1 Wds1^T + s2 y2 Wds2^T + s3 y3 Wds3^T  (bf16)
        k_mg<4, true, true><<<mgGrid, 256, 0, stream>>>(
            xb, bufB, bufC, bufD, nullptr,
            Wds[0], Wds[1], Wds[2], Wds[3], nullptr, nullptr, zb, N);
        // out = cb + W0c x + s0 y0 Wsd0^T + ... + s3 y3 Wsd3^T  (fp32)
        k_mg<5, true, false><<<mgGrid, 256, 0, stream>>>(
            xb, bufA, bufB, bufC, bufD,
            W0c, Wsd[0], Wsd[1], Wsd[2], Wsd[3], cb, out, N);
        // out += A^T z
        k_spmm_acc<<<spmmGrid, 256, 0, stream>>>(zb, out, cptr, adjT, inv_c, N, idxbits);
    } else {
        // fallback: round-5 structure with 2 rotating buffers (8 SpMMs)
        k_spmm<<<spmmGrid, 256, 0, stream>>>(xb, bufA, rptr, adj, inv_r, N, idxbits);
        k_spmm<<<spmmGrid, 256, 0, stream>>>(xb, bufB, cptr, adjT, inv_c, N, idxbits);
        k_mg<3, true, false><<<mgGrid, 256, 0, stream>>>(
            xb, bufA, bufB, nullptr, nullptr,
            W0c, Wsd[0], Wds[0], nullptr, nullptr, cb, out, N);
        unsigned short* ycur = bufA;
        unsigned short* yfree = bufB;
        for (int i = 1; i < 4; i++) {
            k_spmm<<<spmmGrid, 256, 0, stream>>>(ycur, yfree, rptr, adj, inv_r, N, idxbits);
            k_spmm<<<spmmGrid, 256, 0, stream>>>(yfree, ycur, cptr, adjT, inv_c, N, idxbits);
            k_mg<2, false, false><<<mgGrid, 256, 0, stream>>>(
                yfree, ycur, nullptr, nullptr, nullptr,
                Wsd[i], Wds[i], nullptr, nullptr, nullptr, nullptr, out, N);
            unsigned short* t = ycur; ycur = yfree; yfree = t;
        }
    }
}

// Round 12
// 514.287 us; speedup vs baseline: 1.3829x; 1.0332x over previous
//
#include <hip/hip_runtime.h>
#include <hip/hip_bf16.h>

#define DIM 64
#define SCAN_CHUNK 2048
#define NCH 128        // edge chunks per side (LDS-histogram build)
#define HWORDS 32768   // 128 KB static LDS histogram

typedef __bf16 bf16v8 __attribute__((ext_vector_type(8)));
typedef float f32v4 __attribute__((ext_vector_type(4)));

static inline int idiv(int a, int b) { return (a + b - 1) / b; }

__device__ inline unsigned short f2b(float f) {
    __hip_bfloat16 h = __float2bfloat16(f);
    return *reinterpret_cast<unsigned short*>(&h);
}
__device__ inline float b2f(unsigned short u) {
    __hip_bfloat16 h;
    *reinterpret_cast<unsigned short*>(&h) = u;
    return __bfloat162float(h);
}

// ================= LDS byte-histogram CSR build (mega path) =================
// cnt layout: [2][NCH][N] bytes (row side then col side), aliased onto bufC+bufD.

// Phase 1: per-(chunk,node) counts; whole node range in byte-packed LDS.
__global__ __launch_bounds__(1024, 1) void k_hist1(const int* __restrict__ row,
                                                   const int* __restrict__ col,
                                                   unsigned char* __restrict__ cnt,
                                                   int E, int N, int C) {
    __shared__ int hsh[HWORDS];
    int b = blockIdx.x;              // 0..2*NCH-1
    int side = b >> 7;
    int lb = b & (NCH - 1);
    const int* key = side ? col : row;
    int words = (N + 3) >> 2;
    for (int i = threadIdx.x; i < words; i += blockDim.x) hsh[i] = 0;
    __syncthreads();
    int e0 = lb * C, e1 = min(e0 + C, E);
    for (int e = e0 + threadIdx.x; e < e1; e += blockDim.x) {
        int v = key[e];
        atomicAdd(&hsh[v >> 2], 1 << ((v & 3) * 8));
    }
    __syncthreads();
    int* my = (int*)(cnt + (size_t)b * N);   // N%4==0 guaranteed by host gate
    int nw = N >> 2;
    for (int i = threadIdx.x; i < nw; i += blockDim.x) my[i] = hsh[i];
}

// Phase 2: per-node exclusive prefix over the NCH chunks (byte offsets, in
// place) + total degree.
__global__ __launch_bounds__(256) void k_prefixB(unsigned char* __restrict__ cnt,
                                                 int* __restrict__ degs, int N) {
    int v = blockIdx.x * blockDim.x + threadIdx.x;
    if (v < 2 * N) {
        int side = (v >= N) ? 1 : 0;
        int node = v - side * N;
        unsigned char* p = cnt + (size_t)side * NCH * N + node;
        int s = 0;
#pragma unroll 8
        for (int b = 0; b < NCH; b++) {
            unsigned char c = p[(size_t)b * N];
            p[(size_t)b * N] = (unsigned char)s;
            s += c;
        }
        degs[v] = s;
    }
}

// Phase 3: replay histogram; old BYTE = unique within-(chunk,node) slot.
// Plain stores (r8: nt scatter regressed — L2 write-combining beats no-RFO).
__global__ __launch_bounds__(1024, 1) void k_fill3(const int* __restrict__ row,
        const int* __restrict__ col,
        const int* __restrict__ rptr, const int* __restrict__ cptr,
        const unsigned char* __restrict__ cnt,
        const int* __restrict__ deg_r, const int* __restrict__ deg_c,
        unsigned* __restrict__ adj, unsigned* __restrict__ adjT,
        int E, int N, int C, int idxbits) {
    __shared__ int hsh[HWORDS];
    int b = blockIdx.x;
    int side = b >> 7;
    int lb = b & (NCH - 1);
    const int* key = side ? col : row;
    const int* oth = side ? row : col;
    const int* ptr = side ? cptr : rptr;
    const int* odeg = side ? deg_r : deg_c;
    unsigned* dst = side ? adjT : adj;
    const unsigned char* my = cnt + (size_t)b * N;
    int words = (N + 3) >> 2;
    for (int i = threadIdx.x; i < words; i += blockDim.x) hsh[i] = 0;
    __syncthreads();
    unsigned dmask = (1u << (32 - idxbits)) - 1u;
    int e0 = lb * C, e1 = min(e0 + C, E);
    for (int e = e0 + threadIdx.x; e < e1; e += blockDim.x) {
        int v = key[e];
        int sh = (v & 3) * 8;
        unsigned old = (unsigned)atomicAdd(&hsh[v >> 2], 1 << sh);
        int slot = (int)((old >> sh) & 255u);
        int o = oth[e];
        unsigned d = min((unsigned)odeg[o], dmask);
        dst[ptr[v] + (int)my[v] + slot] = (unsigned)o | (d << idxbits);
    }
}

// ================= legacy atomic build (fallback path) =================
__global__ void k_degrees(const int* __restrict__ row, const int* __restrict__ col,
                          int* __restrict__ dr, int* __restrict__ dc,
                          unsigned* __restrict__ slot, int E) {
    int e = blockIdx.x * blockDim.x + threadIdx.x;
    if (e < E) {
        unsigned sr = (unsigned)atomicAdd(&dr[row[e]], 1);
        unsigned sc = (unsigned)atomicAdd(&dc[col[e]], 1);
        slot[e] = (sr & 0xFFFFu) | (sc << 16);
    }
}

__global__ void k_fill(const int* __restrict__ row, const int* __restrict__ col,
                       const int* __restrict__ rptr, const int* __restrict__ cptr,
                       const unsigned* __restrict__ slot,
                       const int* __restrict__ deg_r, const int* __restrict__ deg_c,
                       unsigned* __restrict__ adj, unsigned* __restrict__ adjT,
                       int E, int idxbits) {
    int e = blockIdx.x * blockDim.x + threadIdx.x;
    if (e < E) {
        int r = row[e], c = col[e];
        unsigned s = slot[e];
        unsigned sr = s & 0xFFFFu;
        unsigned sc = s >> 16;
        unsigned wmask = (1u << (32 - idxbits)) - 1u;
        unsigned wc = (unsigned)min((unsigned)deg_c[c], wmask);
        unsigned wr = (unsigned)min((unsigned)deg_r[r], wmask);
        adj [rptr[r] + sr] = (unsigned)c | (wc << idxbits);
        adjT[cptr[c] + sc] = (unsigned)r | (wr << idxbits);
    }
}

// ================= scans =================
__global__ __launch_bounds__(256) void k_scan_blk(const int* __restrict__ deg_r,
                                                  const int* __restrict__ deg_c,
                                                  int* __restrict__ part, int n, int G) {
    int b = blockIdx.x;
    const int* deg = (b < G) ? deg_r : deg_c;
    int lb = (b < G) ? b : b - G;
    int base = lb * SCAN_CHUNK;
    int t = threadIdx.x;
    int s = 0;
    for (int i = t; i < SCAN_CHUNK; i += 256) {
        int g = base + i;
        if (g < n) s += deg[g];
    }
    __shared__ int red[256];
    red[t] = s;
    __syncthreads();
    for (int off = 128; off > 0; off >>= 1) {
        if (t < off) red[t] += red[t + off];
        __syncthreads();
    }
    if (t == 0) part[b] = red[0];
}

__global__ __launch_bounds__(1024) void k_scan_top(int* __restrict__ part, int G,
        const float* __restrict__ bs_sd, const float* __restrict__ b0_sd,
        const float* __restrict__ bs_ds, const float* __restrict__ b0_ds,
        float* __restrict__ cb) {
    int t = threadIdx.x;
    if (blockIdx.x == 2) {
        if (t < 64) {
            float ssd = bs_sd[t] + b0_sd[t];
            float sds = bs_ds[t] + b0_ds[t];
            float sc = 1.f;
            for (int i = 1; i < 4; i++) {
                sc *= 0.5f;
                ssd += bs_sd[i * 64 + t] * sc;
                sds += bs_ds[i * 64 + t] * sc;
            }
            cb[t] = 0.5f * ssd + 0.5f * sds;  // ALPHA = 0.5
        }
        return;
    }
    int* p = part + ((blockIdx.x == 0) ? 0 : G);
    __shared__ int sums[1024];
    sums[t] = (t < G) ? p[t] : 0;
    __syncthreads();
    for (int off = 1; off < 1024; off <<= 1) {
        int v = (t >= off) ? sums[t - off] : 0;
        __syncthreads();
        sums[t] += v;
        __syncthreads();
    }
    if (t < G) p[t] = (t == 0) ? 0 : sums[t - 1];
}

__global__ __launch_bounds__(256) void k_scan_fin(const int* __restrict__ deg_r,
                                                  const int* __restrict__ deg_c,
                                                  const int* __restrict__ part,
                                                  int* __restrict__ rptr, int* __restrict__ cptr,
                                                  float* __restrict__ inv_r, float* __restrict__ inv_c,
                                                  int n, int G) {
    int b = blockIdx.x;
    bool isr = (b < G);
    const int* deg = isr ? deg_r : deg_c;
    int* ptr = isr ? rptr : cptr;
    float* inv = isr ? inv_r : inv_c;
    int lb = isr ? b : b - G;
    int off = part[b];
    int base = lb * SCAN_CHUNK;
    int t = threadIdx.x;
    int start = base + t * 8;
    int v[8];
    int s = 0;
#pragma unroll
    for (int k = 0; k < 8; k++) {
        int g = start + k;
        int d = (g < n) ? deg[g] : 0;
        v[k] = d;
        s += d;
    }
    __shared__ int sums[256];
    sums[t] = s;
    __syncthreads();
    for (int o = 1; o < 256; o <<= 1) {
        int x = (t >= o) ? sums[t - o] : 0;
        __syncthreads();
        sums[t] += x;
        __syncthreads();
    }
    int run = off + ((t == 0) ? 0 : sums[t - 1]);
#pragma unroll
    for (int k = 0; k < 8; k++) {
        int g = start + k;
        if (g < n) {
            ptr[g] = run;
            inv[g] = (v[k] > 0) ? rsqrtf((float)v[k]) : 0.f;
            run += v[k];
        }
    }
    if (t == 255 && lb == G - 1) ptr[n] = run;  // grand total
}

// ================= misc prep =================
__global__ void k_xcast(const float* __restrict__ x, unsigned short* __restrict__ xb, int total) {
    int i = (blockIdx.x * blockDim.x + threadIdx.x) * 4;
    if (i < total) {
        float4 v = *reinterpret_cast<const float4*>(x + i);
        ushort4 o;
        o.x = f2b(v.x); o.y = f2b(v.y); o.z = f2b(v.z); o.w = f2b(v.w);
        *reinterpret_cast<ushort4*>(xb + i) = o;
    }
}

__global__ void k_wprep(const float* __restrict__ Ws_sd, const float* __restrict__ Ws_ds,
                        const float* __restrict__ W0_sd, const float* __restrict__ W0_ds,
                        unsigned short* __restrict__ Wall) {
    int i = blockIdx.x * blockDim.x + threadIdx.x;  // 9*4096 total
    if (i >= 9 * 4096) return;
    int m = i >> 12, src = i & 4095;
    float v;
    if (m == 0) {
        v = 0.5f * (W0_sd[src] + W0_ds[src]);
    } else if (m < 5) {
        int hop = m - 1;
        v = Ws_sd[hop * 4096 + src] * (0.5f / (float)(1 << hop));
    } else {
        int hop = m - 5;
        v = Ws_ds[hop * 4096 + src] * (0.5f / (float)(1 << hop));
    }
    Wall[i] = f2b(v);
}

// ================= SpMM — oct-edge groups: each 8-lane group processes one
// edge, 16 B/lane (uint4 = 8 bf16). 8 edges per wave VMEM instruction pair;
// adj addresses per iteration are consecutive (coalesced 32 B). unroll 2
// puts the whole avg-deg-16 row in flight (~32 cache lines/wave). Reduce via
// shfl_xor(32,16,8); group 0 writes 16 B/lane. =================
__global__ __launch_bounds__(256) void k_spmm(const unsigned short* __restrict__ h,
                                              unsigned short* __restrict__ out,
                                              const int* __restrict__ ptr,
                                              const unsigned* __restrict__ adj,
                                              const float* __restrict__ inv_self,
                                              int n, int idxbits) {
    int gw = (blockIdx.x * blockDim.x + threadIdx.x) >> 6;
    int lane = threadIdx.x & 63;
    if (gw >= n) return;
    int grp = lane >> 3, m = lane & 7;
    int beg = ptr[gw], end = ptr[gw + 1];
    unsigned imask = (1u << idxbits) - 1u;
    float a0 = 0.f, a1 = 0.f, a2 = 0.f, a3 = 0.f;
    float a4 = 0.f, a5 = 0.f, a6 = 0.f, a7 = 0.f;
#pragma unroll 2
    for (int j = beg + grp; j < end; j += 8) {
        unsigned p = adj[j];
        float w = rsqrtf((float)(p >> idxbits));
        uint4 hv = *reinterpret_cast<const uint4*>(
            h + (size_t)(p & imask) * DIM + 8 * m);
        a0 = fmaf(w, b2f((unsigned short)(hv.x & 0xFFFFu)), a0);
        a1 = fmaf(w, b2f((unsigned short)(hv.x >> 16)), a1);
        a2 = fmaf(w, b2f((unsigned short)(hv.y & 0xFFFFu)), a2);
        a3 = fmaf(w, b2f((unsigned short)(hv.y >> 16)), a3);
        a4 = fmaf(w, b2f((unsigned short)(hv.z & 0xFFFFu)), a4);
        a5 = fmaf(w, b2f((unsigned short)(hv.z >> 16)), a5);
        a6 = fmaf(w, b2f((unsigned short)(hv.w & 0xFFFFu)), a6);
        a7 = fmaf(w, b2f((unsigned short)(hv.w >> 16)), a7);
    }
    a0 += __shfl_xor(a0, 32); a0 += __shfl_xor(a0, 16); a0 += __shfl_xor(a0, 8);
    a1 += __shfl_xor(a1, 32); a1 += __shfl_xor(a1, 16); a1 += __shfl_xor(a1, 8);
    a2 += __shfl_xor(a2, 32); a2 += __shfl_xor(a2, 16); a2 += __shfl_xor(a2, 8);
    a3 += __shfl_xor(a3, 32); a3 += __shfl_xor(a3, 16); a3 += __shfl_xor(a3, 8);
    a4 += __shfl_xor(a4, 32); a4 += __shfl_xor(a4, 16); a4 += __shfl_xor(a4, 8);
    a5 += __shfl_xor(a5, 32); a5 += __shfl_xor(a5, 16); a5 += __shfl_xor(a5, 8);
    a6 += __shfl_xor(a6, 32); a6 += __shfl_xor(a6, 16); a6 += __shfl_xor(a6, 8);
    a7 += __shfl_xor(a7, 32); a7 += __shfl_xor(a7, 16); a7 += __shfl_xor(a7, 8);
    if (grp == 0) {
        float iv = inv_self[gw];
        uint4 o;
        o.x = (unsigned)f2b(iv * a0) | ((unsigned)f2b(iv * a1) << 16);
        o.y = (unsigned)f2b(iv * a2) | ((unsigned)f2b(iv * a3) << 16);
        o.z = (unsigned)f2b(iv * a4) | ((unsigned)f2b(iv * a5) << 16);
        o.w = (unsigned)f2b(iv * a6) | ((unsigned)f2b(iv * a7) << 16);
        *reinterpret_cast<uint4*>(out + (size_t)gw * DIM + 8 * m) = o;
    }
}

__global__ __launch_bounds__(256) void k_spmm_acc(const unsigned short* __restrict__ h,
                                                  float* __restrict__ out,
                                                  const int* __restrict__ ptr,
                                                  const unsigned* __restrict__ adj,
                                                  const float* __restrict__ inv_self,
                                                  int n, int idxbits) {
    int gw = (blockIdx.x * blockDim.x + threadIdx.x) >> 6;
    int lane = threadIdx.x & 63;
    if (gw >= n) return;
    int grp = lane >> 3, m = lane & 7;
    int beg = ptr[gw], end = ptr[gw + 1];
    unsigned imask = (1u << idxbits) - 1u;
    float a0 = 0.f, a1 = 0.f, a2 = 0.f, a3 = 0.f;
    float a4 = 0.f, a5 = 0.f, a6 = 0.f, a7 = 0.f;
#pragma unroll 2
    for (int j = beg + grp; j < end; j += 8) {
        unsigned p = adj[j];
        float w = rsqrtf((float)(p >> idxbits));
        uint4 hv = *reinterpret_cast<const uint4*>(
            h + (size_t)(p & imask) * DIM + 8 * m);
        a0 = fmaf(w, b2f((unsigned short)(hv.x & 0xFFFFu)), a0);
        a1 = fmaf(w, b2f((unsigned short)(hv.x >> 16)), a1);
        a2 = fmaf(w, b2f((unsigned short)(hv.y & 0xFFFFu)), a2);
        a3 = fmaf(w, b2f((unsigned short)(hv.y >> 16)), a3);
        a4 = fmaf(w, b2f((unsigned short)(hv.z & 0xFFFFu)), a4);
        a5 = fmaf(w, b2f((unsigned short)(hv.z >> 16)), a5);
        a6 = fmaf(w, b2f((unsigned short)(hv.w & 0xFFFFu)), a6);
        a7 = fmaf(w, b2f((unsigned short)(hv.w >> 16)), a7);
    }
    a0 += __shfl_xor(a0, 32); a0 += __shfl_xor(a0, 16); a0 += __shfl_xor(a0, 8);
    a1 += __shfl_xor(a1, 32); a1 += __shfl_xor(a1, 16); a1 += __shfl_xor(a1, 8);
    a2 += __shfl_xor(a2, 32); a2 += __shfl_xor(a2, 16); a2 += __shfl_xor(a2, 8);
    a3 += __shfl_xor(a3, 32); a3 += __shfl_xor(a3, 16); a3 += __shfl_xor(a3, 8);
    a4 += __shfl_xor(a4, 32); a4 += __shfl_xor(a4, 16); a4 += __shfl_xor(a4, 8);
    a5 += __shfl_xor(a5, 32); a5 += __shfl_xor(a5, 16); a5 += __shfl_xor(a5, 8);
    a6 += __shfl_xor(a6, 32); a6 += __shfl_xor(a6, 16); a6 += __shfl_xor(a6, 8);
    a7 += __shfl_xor(a7, 32); a7 += __shfl_xor(a7, 16); a7 += __shfl_xor(a7, 8);
    if (grp == 0) {
        float iv = inv_self[gw];
        float4* p0 = reinterpret_cast<float4*>(out + (size_t)gw * DIM + 8 * m);
        float4 v0 = p0[0];
        v0.x += iv * a0; v0.y += iv * a1; v0.z += iv * a2; v0.w += iv * a3;
        p0[0] = v0;
        float4 v1 = p0[1];
        v1.x += iv * a4; v1.y += iv * a5; v1.z += iv * a6; v1.w += iv * a7;
        p0[1] = v1;
    }
}

// ================= multi-matrix MFMA GEMM =================
template <int NM, bool INIT, bool BF16OUT>
__global__ __launch_bounds__(256, 2) void k_mg(
        const unsigned short* __restrict__ h0, const unsigned short* __restrict__ h1,
        const unsigned short* __restrict__ h2, const unsigned short* __restrict__ h3,
        const unsigned short* __restrict__ h4,
        const unsigned short* __restrict__ W0, const unsigned short* __restrict__ W1,
        const unsigned short* __restrict__ W2, const unsigned short* __restrict__ W3,
        const unsigned short* __restrict__ W4,
        const float* __restrict__ cb, void* __restrict__ outv, int n) {
    const unsigned short* hs[5] = {h0, h1, h2, h3, h4};
    const unsigned short* Ws[5] = {W0, W1, W2, W3, W4};
    float* outf = (float*)outv;
    unsigned short* outb = (unsigned short*)outv;
    int lane = threadIdx.x & 63;
    int quad = lane >> 4;
    int l16 = lane & 15;
    int nmax = n - 1;

    bf16v8 w[NM][4][2];
#pragma unroll
    for (int m = 0; m < NM; m++)
#pragma unroll
        for (int ot = 0; ot < 4; ot++)
#pragma unroll
            for (int kh = 0; kh < 2; kh++)
                w[m][ot][kh] = *reinterpret_cast<const bf16v8*>(
                    Ws[m] + (size_t)(ot * 16 + l16) * 64 + kh * 32 + quad * 8);

    float bias[4];
    if (INIT) {
#pragma unroll
        for (int ot = 0; ot < 4; ot++) bias[ot] = cb ? cb[ot * 16 + l16] : 0.f;
    }
    int tiles_all = (n + 15) >> 4;
    int wave = (blockIdx.x * blockDim.x + threadIdx.x) >> 6;
    int nw = (gridDim.x * blockDim.x) >> 6;
    for (int t = wave; t < tiles_all; t += nw) {
        int row0 = t << 4;
        int arow = min(row0 + l16, nmax);
        bf16v8 a[NM][2];
#pragma unroll
        for (int m = 0; m < NM; m++) {
            const bf16v8* p = reinterpret_cast<const bf16v8*>(hs[m] + (size_t)arow * 64 + quad * 8);
            a[m][0] = p[0];
            a[m][1] = p[4];
        }
        f32v4 acc[4];
        if (INIT) {
#pragma unroll
            for (int ot = 0; ot < 4; ot++) {
                float b = bias[ot];
                acc[ot] = f32v4{b, b, b, b};
            }
        } else {
#pragma unroll
            for (int ot = 0; ot < 4; ot++)
#pragma unroll
                for (int r = 0; r < 4; r++)
                    acc[ot][r] = outf[(size_t)min(row0 + quad * 4 + r, nmax) * 64 + ot * 16 + l16];
        }
#pragma unroll
        for (int ot = 0; ot < 4; ot++)
#pragma unroll
            for (int m = 0; m < NM; m++) {
                acc[ot] = __builtin_amdgcn_mfma_f32_16x16x32_bf16(a[m][0], w[m][ot][0], acc[ot], 0, 0, 0);
                acc[ot] = __builtin_amdgcn_mfma_f32_16x16x32_bf16(a[m][1], w[m][ot][1], acc[ot], 0, 0, 0);
            }
#pragma unroll
        for (int ot = 0; ot < 4; ot++)
#pragma unroll
            for (int r = 0; r < 4; r++) {
                int rr = row0 + quad * 4 + r;
                if (rr < n) {
                    if (BF16OUT) outb[(size_t)rr * 64 + ot * 16 + l16] = f2b(acc[ot][r]);
                    else         outf[(size_t)rr * 64 + ot * 16 + l16] = acc[ot][r];
                }
            }
    }
}

extern "C" void kernel_launch(void* const* d_in, const int* in_sizes, int n_in,
                              void* d_out, int out_size, void* d_ws, size_t ws_size,
                              hipStream_t stream) {
    const float* x     = (const float*)d_in[0];
    const int*   ei    = (const int*)d_in[1];
    const float* Ws_sd = (const float*)d_in[2];
    const float* bs_sd = (const float*)d_in[3];
    const float* Ws_ds = (const float*)d_in[4];
    const float* bs_ds = (const float*)d_in[5];
    const float* W0_sd = (const float*)d_in[6];
    const float* b0_sd = (const float*)d_in[7];
    const float* W0_ds = (const float*)d_in[8];
    const float* b0_ds = (const float*)d_in[9];

    int N = in_sizes[0] / DIM;
    int E = in_sizes[1] / 2;
    const int* row = ei;
    const int* col = ei + E;
    float* out = (float*)d_out;

    int G = idiv(N, SCAN_CHUNK);
    int idxbits = 1;
    while ((1 << idxbits) < N) idxbits++;

    char* wsp = (char*)d_ws;
    auto alloc = [&](size_t bytes) -> void* {
        void* p = (void*)wsp;
        wsp += ((bytes + 63) / 64) * 64;
        return p;
    };
    size_t bufBytes = ((((size_t)N * DIM * 2) + 63) / 64) * 64;

    int* degs   = (int*)alloc((size_t)2 * N * 4);
    int* deg_r  = degs;
    int* deg_c  = degs + N;
    int* rptr   = (int*)alloc(((size_t)N + 1) * 4);
    int* cptr   = (int*)alloc(((size_t)N + 1) * 4);
    unsigned* adj  = (unsigned*)alloc((size_t)E * 4);
    unsigned* adjT = (unsigned*)alloc((size_t)E * 4);
    unsigned short* xb = (unsigned short*)alloc((size_t)N * DIM * 2);
    float* invs = (float*)alloc((size_t)2 * N * 4);
    float* inv_r = invs;
    float* inv_c = invs + N;
    float* cb   = (float*)alloc(64 * 4);
    unsigned short* Wall = (unsigned short*)alloc((size_t)9 * 4096 * 2);
    int* part   = (int*)alloc((size_t)2 * G * 4);
    unsigned* slot = (unsigned*)alloc((size_t)E * 4);   // fallback path only
    unsigned short* zb = (unsigned short*)alloc((size_t)N * DIM * 2);

    size_t fixed_used = (size_t)(wsp - (char*)d_ws);
    bool mega = (fixed_used + 4 * bufBytes) <= ws_size;

    unsigned short* bufA = (unsigned short*)alloc((size_t)N * DIM * 2);
    unsigned short* bufB = (unsigned short*)alloc((size_t)N * DIM * 2);
    unsigned short* bufC = mega ? (unsigned short*)alloc((size_t)N * DIM * 2) : nullptr;
    unsigned short* bufD = mega ? (unsigned short*)alloc((size_t)N * DIM * 2) : nullptr;

    // cnt [2][NCH][N] bytes = 256N aliases bufC+bufD (= 2*128N bytes, exact fit);
    // consumed by k_fill3 before y2/y3 first write bufC/bufD.
    unsigned char* cnt = (unsigned char*)bufC;
    bool ldsb = mega && (N <= HWORDS * 4) && ((N & 3) == 0);
    int C = idiv(E, NCH);

    if (ldsb) {
        k_hist1<<<2 * NCH, 1024, 0, stream>>>(row, col, cnt, E, N, C);
        k_prefixB<<<idiv(2 * N, 256), 256, 0, stream>>>(cnt, degs, N);
    } else {
        hipMemsetAsync(degs, 0, (size_t)2 * N * sizeof(int), stream);
        k_degrees<<<idiv(E, 256), 256, 0, stream>>>(row, col, deg_r, deg_c, slot, E);
    }
    k_scan_blk<<<2 * G, 256, 0, stream>>>(deg_r, deg_c, part, N, G);
    k_scan_top<<<3, 1024, 0, stream>>>(part, G, bs_sd, b0_sd, bs_ds, b0_ds, cb);
    k_scan_fin<<<2 * G, 256, 0, stream>>>(deg_r, deg_c, part, rptr, cptr, inv_r, inv_c, N, G);
    if (ldsb) {
        k_fill3<<<2 * NCH, 1024, 0, stream>>>(row, col, rptr, cptr, cnt,
                                              deg_r, deg_c, adj, adjT, E, N, C, idxbits);
    } else {
        k_fill<<<idiv(E, 256), 256, 0, stream>>>(row, col, rptr, cptr, slot,
                                                 deg_r, deg_c, adj, adjT, E, idxbits);
    }
    k_xcast<<<idiv(N * DIM / 4, 256), 256, 0, stream>>>(x, xb, N * DIM);
    k_wprep<<<144, 256, 0, stream>>>(Ws_sd, Ws_ds, W0_sd, W0_ds, Wall);

    const unsigned short* W0c = Wall;
    const unsigned short* Wsd[4] = {Wall + 4096, Wall + 2 * 4096, Wall + 3 * 4096, Wall + 4 * 4096};
    const unsigned short* Wds[4] = {Wall + 5 * 4096, Wall + 6 * 4096, Wall + 7 * 4096, Wall + 8 * 4096};

    int spmmGrid = idiv(N * 64, 256);
    int mgGrid = 512;

    if (mega) {
        // A-chain: y0..y3
        k_spmm<<<spmmGrid, 256, 0, stream>>>(xb, bufA, rptr, adj, inv_r, N, idxbits);    // y0
        k_spmm<<<spmmGrid, 256, 0, stream>>>(bufA, bufB, rptr, adj, inv_r, N, idxbits);  // y1
        k_spmm<<<spmmGrid, 256, 0, stream>>>(bufB, bufC, rptr, adj, inv_r, N, idxbits);  // y2
        k_spmm<<<spmmGrid, 256, 0, stream>>>(bufC, bufD, rptr, adj, inv_r, N, idxbits);  // y3
        // z = s0 x Wds0^T + s1 y1 Wds1^T + s2 y2 Wds2^T + s3 y3 Wds3^T  (bf16)
        k_mg<4, true, true><<<mgGrid, 256, 0, stream>>>(
            xb, bufB, bufC, bufD, nullptr,
            Wds[0], Wds[1], Wds[2], Wds[3], nullptr, nullptr, zb, N);
        // out = cb + W0c x + s0 y0 Wsd0^T + ... + s3 y3 Wsd3^T  (fp32)
        k_mg<5, true, false><<<mgGrid, 256, 0, stream>>>(
            xb, bufA, bufB, bufC, bufD,
            W0c, Wsd[0], Wsd[1], Wsd[2], Wsd[3], cb, out, N);
        // out += A^T z
        k_spmm_acc<<<spmmGrid, 256, 0, stream>>>(zb, out, cptr, adjT, inv_c, N, idxbits);
    } else {
        // fallback: round-5 structure with 2 rotating buffers (8 SpMMs)
        k_spmm<<<spmmGrid, 256, 0, stream>>>(xb, bufA, rptr, adj, inv_r, N, idxbits);
        k_spmm<<<spmmGrid, 256, 0, stream>>>(xb, bufB, cptr, adjT, inv_c, N, idxbits);
        k_mg<3, true, false><<<mgGrid, 256, 0, stream>>>(
            xb, bufA, bufB, nullptr, nullptr,
            W0c, Wsd[0], Wds[0], nullptr, nullptr, cb, out, N);
        unsigned short* ycur = bufA;
        unsigned short* yfree = bufB;
        for (int i = 1; i < 4; i++) {
            k_spmm<<<spmmGrid, 256, 0, stream>>>(ycur, yfree, rptr, adj, inv_r, N, idxbits);
            k_spmm<<<spmmGrid, 256, 0, stream>>>(yfree, ycur, cptr, adjT, inv_c, N, idxbits);
            k_mg<2, false, false><<<mgGrid, 256, 0, stream>>>(
                yfree, ycur, nullptr, nullptr, nullptr,
                Wsd[i], Wds[i], nullptr, nullptr, nullptr, nullptr, out, N);
            unsigned short* t = ycur; ycur = yfree; yfree = t;
        }
    }
}